// Round 2
// baseline (1815.952 us; speedup 1.0000x reference)
//
#include <hip/hip_runtime.h>

typedef unsigned short u16;
typedef short short8_t __attribute__((ext_vector_type(8)));
typedef float f32x4 __attribute__((ext_vector_type(4)));

#define SL 128
#define DM 256
#define RK 32
#define SEQ 512
#define NB 4
#define NCHUNK 16
#define ICH 8

__device__ __forceinline__ float bf2f(u16 u) {
  return __uint_as_float(((unsigned int)u) << 16);
}
__device__ __forceinline__ u16 f2bf(float f) {
  unsigned int x = __float_as_uint(f);
  x += 0x7fffu + ((x >> 16) & 1u);
  return (u16)(x >> 16);
}
__device__ __forceinline__ float ldw(const u16* p) { return bf2f(*p); }
__device__ __forceinline__ float ldw(const float* p) { return *p; }

// ----------------- f32 -> bf16 conversion (vectorized) ----------------------
__global__ __launch_bounds__(256) void cvt_k(const float* __restrict__ in,
                                             u16* __restrict__ out, int n4) {
  for (int i = blockIdx.x * blockDim.x + threadIdx.x; i < n4;
       i += gridDim.x * blockDim.x) {
    float4 v = ((const float4*)in)[i];
    u16 o0 = f2bf(v.x), o1 = f2bf(v.y), o2 = f2bf(v.z), o3 = f2bf(v.w);
    unsigned int lo = (unsigned int)o0 | ((unsigned int)o1 << 16);
    unsigned int hi = (unsigned int)o2 | ((unsigned int)o3 << 16);
    ((uint2*)out)[i] = make_uint2(lo, hi);
  }
}

// ---------------- embedding: x = tok[id] + pos[s] (bf16 out) ----------------
__global__ __launch_bounds__(256) void embed_k(const int* __restrict__ ids,
    const float* __restrict__ tok, const float* __restrict__ pos,
    u16* __restrict__ xbf) {
  int bs = blockIdx.x, d = threadIdx.x;
  int id = ids[bs];
  int s = bs & (SEQ - 1);
  float v = tok[(size_t)id * DM + d] + pos[(size_t)s * DM + d];
  xbf[(size_t)bs * DM + d] = f2bf(v);
}

// ------------- generic NT GEMM: C[M,N] = A[M,256] * B[N,256]^T --------------
// bf16 inputs, f32 output. BM=BN=64, K=256 staged once in LDS.
// XOR swizzle (elem ^= (row&7)<<3) => conflict-free ds_read_b128 fragments.
__global__ __launch_bounds__(256) void gemm_nt(const u16* __restrict__ A,
    const u16* __restrict__ Bw, float* __restrict__ Cout, int N) {
  __shared__ u16 s_a[64 * 256];
  __shared__ u16 s_b[64 * 256];
  int tid = threadIdx.x;
  int m0 = blockIdx.x * 64, n0 = blockIdx.y * 64;
  for (int c = tid; c < 2048; c += 256) {
    int row = c >> 5;
    int ec = (c & 31) << 3;
    short8_t va = *(const short8_t*)(A + (size_t)(m0 + row) * 256 + ec);
    short8_t vb = *(const short8_t*)(Bw + (size_t)(n0 + row) * 256 + ec);
    int sw = ec ^ ((row & 7) << 3);
    *(short8_t*)(&s_a[row * 256 + sw]) = va;
    *(short8_t*)(&s_b[row * 256 + sw]) = vb;
  }
  __syncthreads();
  int lane = tid & 63;
  int w = tid >> 6;
  int wm = (w >> 1) * 32, wn = (w & 1) * 32;
  int lr = lane & 15, lk = (lane >> 4) << 3;
  f32x4 acc00 = {0.f, 0.f, 0.f, 0.f};
  f32x4 acc01 = {0.f, 0.f, 0.f, 0.f};
  f32x4 acc10 = {0.f, 0.f, 0.f, 0.f};
  f32x4 acc11 = {0.f, 0.f, 0.f, 0.f};
#pragma unroll
  for (int ks = 0; ks < 8; ++ks) {
    int ke = ks * 32 + lk;
    int r0 = wm + lr, r1 = wm + 16 + lr;
    int c0 = wn + lr, c1 = wn + 16 + lr;
    short8_t a0 = *(const short8_t*)(&s_a[r0 * 256 + (ke ^ ((r0 & 7) << 3))]);
    short8_t a1 = *(const short8_t*)(&s_a[r1 * 256 + (ke ^ ((r1 & 7) << 3))]);
    short8_t b0 = *(const short8_t*)(&s_b[c0 * 256 + (ke ^ ((c0 & 7) << 3))]);
    short8_t b1 = *(const short8_t*)(&s_b[c1 * 256 + (ke ^ ((c1 & 7) << 3))]);
    acc00 = __builtin_amdgcn_mfma_f32_16x16x32_bf16(a0, b0, acc00, 0, 0, 0);
    acc01 = __builtin_amdgcn_mfma_f32_16x16x32_bf16(a0, b1, acc01, 0, 0, 0);
    acc10 = __builtin_amdgcn_mfma_f32_16x16x32_bf16(a1, b0, acc10, 0, 0, 0);
    acc11 = __builtin_amdgcn_mfma_f32_16x16x32_bf16(a1, b1, acc11, 0, 0, 0);
  }
  int rbase = (lane >> 4) << 2;
#pragma unroll
  for (int i = 0; i < 2; ++i) {
#pragma unroll
    for (int jj = 0; jj < 2; ++jj) {
      f32x4 v = (i == 0) ? (jj == 0 ? acc00 : acc01)
                         : (jj == 0 ? acc10 : acc11);
      int row0 = m0 + wm + i * 16 + rbase;
      int col = n0 + wn + jj * 16 + lr;
#pragma unroll
      for (int q = 0; q < 4; ++q)
        Cout[(size_t)(row0 + q) * (size_t)N + col] = v[q];
    }
  }
}

// ------- input compression attention: softmax over slots, then mask ---------
__global__ __launch_bounds__(128) void attn_in_k(const float* __restrict__ Qi,
    const float* __restrict__ Ksl, const int* __restrict__ am,
    float* __restrict__ Aout) {
  int bs = blockIdx.x, t = threadIdx.x;
  __shared__ float s_q[DM];
  __shared__ float sred[2];
  s_q[t] = Qi[(size_t)bs * DM + t];
  s_q[t + 128] = Qi[(size_t)bs * DM + t + 128];
  __syncthreads();
  const float* kr = Ksl + (size_t)t * DM;
  float sc = 0.f;
#pragma unroll 8
  for (int d = 0; d < DM; ++d) sc += s_q[d] * kr[d];
  sc *= 0.0625f;
  float mx = sc;
#pragma unroll
  for (int m = 1; m < 64; m <<= 1) mx = fmaxf(mx, __shfl_xor(mx, m));
  if ((t & 63) == 0) sred[t >> 6] = mx;
  __syncthreads();
  mx = fmaxf(sred[0], sred[1]);
  float p = expf(sc - mx);
  float sum = p;
#pragma unroll
  for (int m = 1; m < 64; m <<= 1) sum += __shfl_xor(sum, m);
  __syncthreads();
  if ((t & 63) == 0) sred[t >> 6] = sum;
  __syncthreads();
  sum = sred[0] + sred[1];
  p = (p / sum) * (float)am[bs];
  Aout[(size_t)bs * SL + t] = p;
}

// --------- column sums over s: den[b,k] = sum_s A[b,s,k] + 1e-8 -------------
__global__ void colsum_k(const float* __restrict__ A, float* __restrict__ den) {
  int t = blockIdx.x * blockDim.x + threadIdx.x;
  if (t >= NB * SL) return;
  int b = t >> 7, k = t & (SL - 1);
  const float* ap = A + (size_t)b * SEQ * SL + k;
  float s = 0.f;
#pragma unroll 4
  for (int si = 0; si < SEQ; ++si) s += ap[(size_t)si * SL];
  den[t] = s + 1e-8f;
}

// ------ IR[b,k,d] = sum_s A[b,s,k]*Vi[b,s,d] / den;  Hs = H + IR ------------
__global__ __launch_bounds__(256) void irhs_k(const float* __restrict__ A,
    const float* __restrict__ Vi, const float* __restrict__ den,
    const float* __restrict__ H, float* __restrict__ Hs) {
  int k = blockIdx.x, b = blockIdx.y, d = threadIdx.x;
  const float* ap = A + (size_t)b * SEQ * SL + k;
  const float* vp = Vi + (size_t)b * SEQ * DM + d;
  float s = 0.f;
#pragma unroll 4
  for (int si = 0; si < SEQ; ++si)
    s += ap[(size_t)si * SL] * vp[(size_t)si * DM];
  float inv = 1.f / den[b * SL + k];
  Hs[((size_t)b * SL + k) * DM + d] = H[(size_t)k * DM + d] + s * inv;
}

// -------------------- bilinear all-pairs slot mixing ------------------------
// block (j, ic): accumulates over i in [ic*8, ic*8+8), i != j.
// partials[ic][b][j][d]; each W element read exactly once per step.
template <typename WT>
__global__ __launch_bounds__(256) void bilinear_k(const float* __restrict__ Hs,
    const WT* __restrict__ Ws, const WT* __restrict__ Wt,
    float* __restrict__ part) {
  int j = blockIdx.x, ic = blockIdx.y, tid = threadIdx.x;
  int i0 = ic * ICH;
  __shared__ float s_hs[NB][ICH][DM];   // 32 KB
  __shared__ WT s_ws[DM * RK];          // 16 KB bf16 / 32 KB f32
  __shared__ WT s_wt[RK * DM];
  __shared__ float s_inter[2][NB][RK];  // 1 KB
  for (int c = tid; c < (NB * ICH * DM) / 4; c += 256) {
    int fi = c * 4;
    int b = fi >> 11, rest = fi & 2047;
    *(float4*)(&s_hs[0][0][0] + fi) =
        *(const float4*)(Hs + (size_t)b * SL * DM + (size_t)i0 * DM + rest);
  }
  float acc0 = 0.f, acc1 = 0.f, acc2 = 0.f, acc3 = 0.f;
  int half = tid >> 7, bb = (tid >> 5) & 3, rr = tid & 31;
  __syncthreads();
  constexpr int CH = (DM * RK * sizeof(WT)) / 16;  // 16B chunks per slab
  for (int il = 0; il < ICH; ++il) {
    int i = i0 + il;
    if (i == j) continue;  // block-uniform: all threads skip together
    const WT* wp = Ws + (size_t)(i * SL + j) * (DM * RK);
    const WT* tp = Wt + (size_t)(i * SL + j) * (RK * DM);
    for (int c = tid; c < CH; c += 256) {
      ((float4*)s_ws)[c] = ((const float4*)wp)[c];
      ((float4*)s_wt)[c] = ((const float4*)tp)[c];
    }
    __syncthreads();
    {  // inter[b,r] = sum_d Hs[b,i,d] * Ws[i,j,d,r], split over two d-halves
      float sum = 0.f;
      const float* hp = &s_hs[bb][il][half * 128];
      const WT* wq = s_ws + (half * 128) * RK + rr;
#pragma unroll 8
      for (int d = 0; d < 128; ++d) sum += hp[d] * ldw(wq + d * RK);
      s_inter[half][bb][rr] = sum;
    }
    __syncthreads();
    if (tid < 128) s_inter[0][bb][rr] += s_inter[1][bb][rr];
    __syncthreads();
    {  // influence[b,j,d] += sum_r inter[b,r] * Wt[i,j,r,d]; thread owns d=tid
#pragma unroll 8
      for (int r = 0; r < RK; ++r) {
        float wv = ldw(s_wt + r * DM + tid);
        acc0 += s_inter[0][0][r] * wv;
        acc1 += s_inter[0][1][r] * wv;
        acc2 += s_inter[0][2][r] * wv;
        acc3 += s_inter[0][3][r] * wv;
      }
    }
    __syncthreads();
  }
  size_t base = (((size_t)ic * NB) * SL + j) * DM + tid;
  part[base] = acc0;
  part[base + (size_t)1 * SL * DM] = acc1;
  part[base + (size_t)2 * SL * DM] = acc2;
  part[base + (size_t)3 * SL * DM] = acc3;
}

// ------- reduce partials + relu + residual + LayerNorm (per (b,j) row) ------
__global__ __launch_bounds__(256) void ln_k(float* __restrict__ Hs,
    const float* __restrict__ part, const float* __restrict__ g,
    const float* __restrict__ be, int last, u16* __restrict__ Hs_bf) {
  int j = blockIdx.x, b = blockIdx.y, d = threadIdx.x;
  size_t base = ((size_t)b * SL + j) * DM + d;
  float inf = 0.f;
#pragma unroll
  for (int icc = 0; icc < NCHUNK; ++icc)
    inf += part[(((size_t)icc * NB + b) * SL + j) * DM + d];
  float h = Hs[base] + fmaxf(inf, 0.f);
  float s1 = h, s2 = h * h;
#pragma unroll
  for (int m = 1; m < 64; m <<= 1) {
    s1 += __shfl_xor(s1, m);
    s2 += __shfl_xor(s2, m);
  }
  __shared__ float r1[4], r2[4];
  int wv = d >> 6;
  if ((d & 63) == 0) { r1[wv] = s1; r2[wv] = s2; }
  __syncthreads();
  s1 = r1[0] + r1[1] + r1[2] + r1[3];
  s2 = r2[0] + r2[1] + r2[2] + r2[3];
  float mu = s1 * (1.f / 256.f);
  float var = s2 * (1.f / 256.f) - mu * mu;
  float o = (h - mu) * rsqrtf(var + 1e-5f) * g[d] + be[d];
  Hs[base] = o;
  if (last) Hs_bf[base] = f2bf(o);
}

// ----------------- output expansion attention + Y (bf16) --------------------
__global__ __launch_bounds__(128) void attn_out_k(const float* __restrict__ Qo,
    const float* __restrict__ Kf, const float* __restrict__ Vf,
    u16* __restrict__ Ybf) {
  int bs = blockIdx.x, t = threadIdx.x;
  int b = bs >> 9;
  __shared__ float s_q[DM];
  __shared__ float s_p[SL];
  __shared__ float sred[2];
  s_q[t] = Qo[(size_t)bs * DM + t];
  s_q[t + 128] = Qo[(size_t)bs * DM + t + 128];
  __syncthreads();
  const float* kr = Kf + ((size_t)b * SL + t) * DM;
  float sc = 0.f;
#pragma unroll 8
  for (int d = 0; d < DM; ++d) sc += s_q[d] * kr[d];
  sc *= 0.0625f;
  float mx = sc;
#pragma unroll
  for (int m = 1; m < 64; m <<= 1) mx = fmaxf(mx, __shfl_xor(mx, m));
  if ((t & 63) == 0) sred[t >> 6] = mx;
  __syncthreads();
  mx = fmaxf(sred[0], sred[1]);
  float p = expf(sc - mx);
  float sum = p;
#pragma unroll
  for (int m = 1; m < 64; m <<= 1) sum += __shfl_xor(sum, m);
  __syncthreads();
  if ((t & 63) == 0) sred[t >> 6] = sum;
  __syncthreads();
  sum = sred[0] + sred[1];
  s_p[t] = p / sum;
  __syncthreads();
  for (int dd = t; dd < DM; dd += 128) {
    float y = 0.f;
    const float* vp = Vf + (size_t)b * SL * DM + dd;
#pragma unroll 8
    for (int k2 = 0; k2 < SL; ++k2) y += s_p[k2] * vp[(size_t)k2 * DM];
    Ybf[(size_t)bs * DM + dd] = f2bf(y);
  }
}

extern "C" void kernel_launch(void* const* d_in, const int* in_sizes, int n_in,
                              void* d_out, int out_size, void* d_ws,
                              size_t ws_size, hipStream_t stream) {
  (void)in_sizes; (void)n_in; (void)out_size;
  const int* ids = (const int*)d_in[0];
  const int* amask = (const int*)d_in[1];
  const float* tok = (const float*)d_in[2];
  const float* pos = (const float*)d_in[3];
  const float* Hsl = (const float*)d_in[4];
  const float* Ws = (const float*)d_in[5];
  const float* Wt = (const float*)d_in[6];
  const float* wq_in = (const float*)d_in[7];
  const float* wk_sl = (const float*)d_in[8];
  const float* wv_in = (const float*)d_in[9];
  const float* wq_out = (const float*)d_in[10];
  const float* wk_fin = (const float*)d_in[11];
  const float* wv_fin = (const float*)d_in[12];
  const float* w_out = (const float*)d_in[13];
  const float* lng = (const float*)d_in[14];
  const float* lnb = (const float*)d_in[15];

  char* base = (char*)d_ws;
  size_t used = 0;
  auto carve = [&](size_t bytes) {
    void* r = base + used;
    used += (bytes + 255) & ~(size_t)255;
    return r;
  };
  u16* x_bf = (u16*)carve((size_t)2048 * 256 * 2);
  float* Qi = (float*)carve((size_t)2048 * 256 * 4);
  float* Vi = (float*)carve((size_t)2048 * 256 * 4);
  float* Qo = (float*)carve((size_t)2048 * 256 * 4);
  float* Ksl = (float*)carve((size_t)128 * 256 * 4);
  float* Aat = (float*)carve((size_t)4 * 512 * 128 * 4);
  float* den = (float*)carve((size_t)512 * 4);
  float* Hst = (float*)carve((size_t)4 * 128 * 256 * 4);
  u16* Hs_bf = (u16*)carve((size_t)4 * 128 * 256 * 2);
  float* part = (float*)carve((size_t)16 * 4 * 128 * 256 * 4);
  float* Kf = (float*)carve((size_t)4 * 128 * 256 * 4);
  float* Vf = (float*)carve((size_t)4 * 128 * 256 * 4);
  u16* Ybf = (u16*)carve((size_t)2048 * 256 * 2);
  u16* Hbf = (u16*)carve((size_t)128 * 256 * 2);
  u16* wbf[6];
  for (int q = 0; q < 6; ++q) wbf[q] = (u16*)carve((size_t)256 * 256 * 2);
  u16* w_out_bf = (u16*)carve((size_t)32000 * 256 * 2);
  const size_t WN = (size_t)128 * 128 * 256 * 32;  // elems of each W tensor
  bool bigws = (used + 2 * WN * 2 + 512) <= ws_size;
  u16* Ws_bf = nullptr;
  u16* Wt_bf = nullptr;
  if (bigws) {
    Ws_bf = (u16*)carve(WN * 2);
    Wt_bf = (u16*)carve(WN * 2);
  }

  auto cvt = [&](const float* in, u16* out, size_t n) {
    int n4 = (int)(n / 4);
    int blocks = (n4 + 255) / 256;
    if (blocks > 2048) blocks = 2048;
    cvt_k<<<blocks, 256, 0, stream>>>(in, out, n4);
  };

  // weight conversions
  const float* sqw[6] = {wq_in, wk_sl, wv_in, wq_out, wk_fin, wv_fin};
  for (int q = 0; q < 6; ++q) cvt(sqw[q], wbf[q], 256 * 256);
  cvt(Hsl, Hbf, 128 * 256);
  cvt(w_out, w_out_bf, (size_t)32000 * 256);
  if (bigws) {
    cvt(Ws, Ws_bf, WN);
    cvt(Wt, Wt_bf, WN);
  }

  embed_k<<<2048, 256, 0, stream>>>(ids, tok, pos, x_bf);
  gemm_nt<<<dim3(32, 4), 256, 0, stream>>>(x_bf, wbf[0], Qi, 256);
  gemm_nt<<<dim3(32, 4), 256, 0, stream>>>(x_bf, wbf[2], Vi, 256);
  gemm_nt<<<dim3(32, 4), 256, 0, stream>>>(x_bf, wbf[3], Qo, 256);
  gemm_nt<<<dim3(2, 4), 256, 0, stream>>>(Hbf, wbf[1], Ksl, 256);
  attn_in_k<<<2048, 128, 0, stream>>>(Qi, Ksl, amask, Aat);
  colsum_k<<<2, 256, 0, stream>>>(Aat, den);
  irhs_k<<<dim3(128, 4), 256, 0, stream>>>(Aat, Vi, den, Hsl, Hst);
  for (int step = 0; step < 6; ++step) {
    if (bigws)
      bilinear_k<u16><<<dim3(128, 16), 256, 0, stream>>>(Hst, Ws_bf, Wt_bf,
                                                         part);
    else
      bilinear_k<float><<<dim3(128, 16), 256, 0, stream>>>(Hst, Ws, Wt, part);
    ln_k<<<dim3(128, 4), 256, 0, stream>>>(Hst, part, lng + step * DM,
                                           lnb + step * DM, step == 5 ? 1 : 0,
                                           Hs_bf);
  }
  gemm_nt<<<dim3(8, 4), 256, 0, stream>>>(Hs_bf, wbf[4], Kf, 256);
  gemm_nt<<<dim3(8, 4), 256, 0, stream>>>(Hs_bf, wbf[5], Vf, 256);
  attn_out_k<<<2048, 128, 0, stream>>>(Qo, Kf, Vf, Ybf);
  gemm_nt<<<dim3(32, 500), 256, 0, stream>>>(Ybf, w_out_bf, (float*)d_out,
                                             32000);
}

// Round 4
// 1311.373 us; speedup vs baseline: 1.3848x; 1.3848x over previous
//
#include <hip/hip_runtime.h>

typedef unsigned short u16;
typedef short short8_t __attribute__((ext_vector_type(8)));
typedef float f32x4 __attribute__((ext_vector_type(4)));

#define SL 128
#define DM 256
#define RK 32
#define SEQ 512
#define NB 4
#define NCHUNK 16
#define ICH 8

__device__ __forceinline__ float bf2f(u16 u) {
  return __uint_as_float(((unsigned int)u) << 16);
}
__device__ __forceinline__ u16 f2bf(float f) {
  unsigned int x = __float_as_uint(f);
  x += 0x7fffu + ((x >> 16) & 1u);
  return (u16)(x >> 16);
}

// ----------------- f32 -> bf16 conversion (vectorized) ----------------------
__global__ __launch_bounds__(256) void cvt_k(const float* __restrict__ in,
                                             u16* __restrict__ out, int n4) {
  for (int i = blockIdx.x * blockDim.x + threadIdx.x; i < n4;
       i += gridDim.x * blockDim.x) {
    float4 v = ((const float4*)in)[i];
    u16 o0 = f2bf(v.x), o1 = f2bf(v.y), o2 = f2bf(v.z), o3 = f2bf(v.w);
    unsigned int lo = (unsigned int)o0 | ((unsigned int)o1 << 16);
    unsigned int hi = (unsigned int)o2 | ((unsigned int)o3 << 16);
    ((uint2*)out)[i] = make_uint2(lo, hi);
  }
}

// ---------------- embedding: x = tok[id] + pos[s] (bf16 out) ----------------
__global__ __launch_bounds__(256) void embed_k(const int* __restrict__ ids,
    const float* __restrict__ tok, const float* __restrict__ pos,
    u16* __restrict__ xbf) {
  int bs = blockIdx.x, d = threadIdx.x;
  int id = ids[bs];
  int s = bs & (SEQ - 1);
  float v = tok[(size_t)id * DM + d] + pos[(size_t)s * DM + d];
  xbf[(size_t)bs * DM + d] = f2bf(v);
}

// ------------- generic NT GEMM: C[M,N] = A[M,256] * B[N,256]^T --------------
__global__ __launch_bounds__(256) void gemm_nt(const u16* __restrict__ A,
    const u16* __restrict__ Bw, float* __restrict__ Cout, int N) {
  __shared__ u16 s_a[64 * 256];
  __shared__ u16 s_b[64 * 256];
  int tid = threadIdx.x;
  int m0 = blockIdx.x * 64, n0 = blockIdx.y * 64;
  for (int c = tid; c < 2048; c += 256) {
    int row = c >> 5;
    int ec = (c & 31) << 3;
    short8_t va = *(const short8_t*)(A + (size_t)(m0 + row) * 256 + ec);
    short8_t vb = *(const short8_t*)(Bw + (size_t)(n0 + row) * 256 + ec);
    int sw = ec ^ ((row & 7) << 3);
    *(short8_t*)(&s_a[row * 256 + sw]) = va;
    *(short8_t*)(&s_b[row * 256 + sw]) = vb;
  }
  __syncthreads();
  int lane = tid & 63;
  int w = tid >> 6;
  int wm = (w >> 1) * 32, wn = (w & 1) * 32;
  int lr = lane & 15, lk = (lane >> 4) << 3;
  f32x4 acc00 = {0.f, 0.f, 0.f, 0.f};
  f32x4 acc01 = {0.f, 0.f, 0.f, 0.f};
  f32x4 acc10 = {0.f, 0.f, 0.f, 0.f};
  f32x4 acc11 = {0.f, 0.f, 0.f, 0.f};
#pragma unroll
  for (int ks = 0; ks < 8; ++ks) {
    int ke = ks * 32 + lk;
    int r0 = wm + lr, r1 = wm + 16 + lr;
    int c0 = wn + lr, c1 = wn + 16 + lr;
    short8_t a0 = *(const short8_t*)(&s_a[r0 * 256 + (ke ^ ((r0 & 7) << 3))]);
    short8_t a1 = *(const short8_t*)(&s_a[r1 * 256 + (ke ^ ((r1 & 7) << 3))]);
    short8_t b0 = *(const short8_t*)(&s_b[c0 * 256 + (ke ^ ((c0 & 7) << 3))]);
    short8_t b1 = *(const short8_t*)(&s_b[c1 * 256 + (ke ^ ((c1 & 7) << 3))]);
    acc00 = __builtin_amdgcn_mfma_f32_16x16x32_bf16(a0, b0, acc00, 0, 0, 0);
    acc01 = __builtin_amdgcn_mfma_f32_16x16x32_bf16(a0, b1, acc01, 0, 0, 0);
    acc10 = __builtin_amdgcn_mfma_f32_16x16x32_bf16(a1, b0, acc10, 0, 0, 0);
    acc11 = __builtin_amdgcn_mfma_f32_16x16x32_bf16(a1, b1, acc11, 0, 0, 0);
  }
  int rbase = (lane >> 4) << 2;
#pragma unroll
  for (int i = 0; i < 2; ++i) {
#pragma unroll
    for (int jj = 0; jj < 2; ++jj) {
      f32x4 v = (i == 0) ? (jj == 0 ? acc00 : acc01)
                         : (jj == 0 ? acc10 : acc11);
      int row0 = m0 + wm + i * 16 + rbase;
      int col = n0 + wn + jj * 16 + lr;
#pragma unroll
      for (int q = 0; q < 4; ++q)
        Cout[(size_t)(row0 + q) * (size_t)N + col] = v[q];
    }
  }
}

// ------- input compression attention: softmax over slots, then mask ---------
__global__ __launch_bounds__(128) void attn_in_k(const float* __restrict__ Qi,
    const float* __restrict__ Ksl, const int* __restrict__ am,
    float* __restrict__ Aout) {
  int bs = blockIdx.x, t = threadIdx.x;
  __shared__ float s_q[DM];
  __shared__ float sred[2];
  s_q[t] = Qi[(size_t)bs * DM + t];
  s_q[t + 128] = Qi[(size_t)bs * DM + t + 128];
  __syncthreads();
  const float* kr = Ksl + (size_t)t * DM;
  float sc = 0.f;
#pragma unroll 8
  for (int d = 0; d < DM; ++d) sc += s_q[d] * kr[d];
  sc *= 0.0625f;
  float mx = sc;
#pragma unroll
  for (int m = 1; m < 64; m <<= 1) mx = fmaxf(mx, __shfl_xor(mx, m));
  if ((t & 63) == 0) sred[t >> 6] = mx;
  __syncthreads();
  mx = fmaxf(sred[0], sred[1]);
  float p = expf(sc - mx);
  float sum = p;
#pragma unroll
  for (int m = 1; m < 64; m <<= 1) sum += __shfl_xor(sum, m);
  __syncthreads();
  if ((t & 63) == 0) sred[t >> 6] = sum;
  __syncthreads();
  sum = sred[0] + sred[1];
  p = (p / sum) * (float)am[bs];
  Aout[(size_t)bs * SL + t] = p;
}

// --------- column sums over s: den[b,k] = sum_s A[b,s,k] + 1e-8 -------------
__global__ void colsum_k(const float* __restrict__ A, float* __restrict__ den) {
  int t = blockIdx.x * blockDim.x + threadIdx.x;
  if (t >= NB * SL) return;
  int b = t >> 7, k = t & (SL - 1);
  const float* ap = A + (size_t)b * SEQ * SL + k;
  float s = 0.f;
#pragma unroll 4
  for (int si = 0; si < SEQ; ++si) s += ap[(size_t)si * SL];
  den[t] = s + 1e-8f;
}

// ------ IR[b,k,d] = sum_s A[b,s,k]*Vi[b,s,d] / den;  Hs = H + IR ------------
__global__ __launch_bounds__(256) void irhs_k(const float* __restrict__ A,
    const float* __restrict__ Vi, const float* __restrict__ den,
    const float* __restrict__ H, float* __restrict__ Hs) {
  int k = blockIdx.x, b = blockIdx.y, d = threadIdx.x;
  const float* ap = A + (size_t)b * SEQ * SL + k;
  const float* vp = Vi + (size_t)b * SEQ * DM + d;
  float s = 0.f;
#pragma unroll 4
  for (int si = 0; si < SEQ; ++si)
    s += ap[(size_t)si * SL] * vp[(size_t)si * DM];
  float inv = 1.f / den[b * SL + k];
  Hs[((size_t)b * SL + k) * DM + d] = H[(size_t)k * DM + d] + s * inv;
}

// -------------------- bilinear all-pairs slot mixing ------------------------
// Wave-per-pair, barrier-free main loop. Block (j, ic): 4 waves, wave w owns
// i in {ic*8+2w, ic*8+2w+1}. MODE 0: read bf16 W. MODE 1: read f32 W, write
// bf16 slabs (fused convert, step 0). MODE 2: read f32, no write (fallback).
template <int MODE>
__global__ __launch_bounds__(256) void bilinear_k(const float* __restrict__ Hs,
    const void* __restrict__ Wsv, const void* __restrict__ Wtv,
    u16* __restrict__ Wsb, u16* __restrict__ Wtb, float* __restrict__ part) {
  constexpr int QN = (MODE == 0) ? 8 : 4;
  int j = blockIdx.x, ic = blockIdx.y, tid = threadIdx.x;
  int wv = tid >> 6, ln = tid & 63;
  __shared__ float s_hs[NB][ICH][DM];   // 32 KB
  __shared__ float s_int[4][NB][RK];    // 2 KB, per-wave slot
  __shared__ float s_acc[4][NB][DM];    // 16 KB, per-wave slot
  int i0 = ic * ICH;
  for (int c = tid; c < (NB * ICH * DM) / 4; c += 256) {
    int fi = c * 4;
    int b = fi >> 11, rest = fi & 2047;
    *(float4*)(&s_hs[0][0][0] + fi) =
        *(const float4*)(Hs + (size_t)b * SL * DM + (size_t)i0 * DM + rest);
  }
  __syncthreads();
  float iacc[NB][QN];
#pragma unroll
  for (int b = 0; b < NB; ++b)
#pragma unroll
    for (int q = 0; q < QN; ++q) iacc[b][q] = 0.f;
#pragma unroll
  for (int ii = 0; ii < 2; ++ii) {
    int il = wv * 2 + ii;
    int i = i0 + il;
    if (i != j) {
      size_t slab = (size_t)(i * SL + j) * (DM * RK);
      float racc[NB][QN];
#pragma unroll
      for (int b = 0; b < NB; ++b)
#pragma unroll
        for (int q = 0; q < QN; ++q) racc[b][q] = 0.f;
      // ---- inter[b,r] = sum_d Hs[b,i,d] * Ws[i,j,d,r] ----
      if constexpr (MODE == 0) {
        const u16* wp = (const u16*)Wsv + slab;
#pragma unroll
        for (int t = 0; t < 16; ++t) {
          short8_t w8 = *(const short8_t*)(wp + t * 512 + ln * 8);
          int d = t * 16 + (ln >> 2);
          float h0 = s_hs[0][il][d], h1 = s_hs[1][il][d];
          float h2 = s_hs[2][il][d], h3 = s_hs[3][il][d];
#pragma unroll
          for (int q = 0; q < 8; ++q) {
            float wf = bf2f((u16)w8[q]);
            racc[0][q] += h0 * wf;
            racc[1][q] += h1 * wf;
            racc[2][q] += h2 * wf;
            racc[3][q] += h3 * wf;
          }
        }
#pragma unroll
        for (int m = 4; m <= 32; m <<= 1)
#pragma unroll
          for (int b = 0; b < NB; ++b)
#pragma unroll
            for (int q = 0; q < 8; ++q)
              racc[b][q] += __shfl_xor(racc[b][q], m);
        if ((ln >> 2) == 0) {
          int r0 = (ln & 3) * 8;
#pragma unroll
          for (int b = 0; b < NB; ++b)
#pragma unroll
            for (int q = 0; q < 8; ++q) s_int[wv][b][r0 + q] = racc[b][q];
        }
      } else {
        const float* wp = (const float*)Wsv + slab;
#pragma unroll 8
        for (int t = 0; t < 32; ++t) {
          float4 w4 = *(const float4*)(wp + t * 256 + ln * 4);
          int d = t * 8 + (ln >> 3);
          float h0 = s_hs[0][il][d], h1 = s_hs[1][il][d];
          float h2 = s_hs[2][il][d], h3 = s_hs[3][il][d];
          racc[0][0] += h0 * w4.x; racc[0][1] += h0 * w4.y;
          racc[0][2] += h0 * w4.z; racc[0][3] += h0 * w4.w;
          racc[1][0] += h1 * w4.x; racc[1][1] += h1 * w4.y;
          racc[1][2] += h1 * w4.z; racc[1][3] += h1 * w4.w;
          racc[2][0] += h2 * w4.x; racc[2][1] += h2 * w4.y;
          racc[2][2] += h2 * w4.z; racc[2][3] += h2 * w4.w;
          racc[3][0] += h3 * w4.x; racc[3][1] += h3 * w4.y;
          racc[3][2] += h3 * w4.z; racc[3][3] += h3 * w4.w;
          if constexpr (MODE == 1) {
            uint2 pk;
            pk.x = (unsigned)f2bf(w4.x) | ((unsigned)f2bf(w4.y) << 16);
            pk.y = (unsigned)f2bf(w4.z) | ((unsigned)f2bf(w4.w) << 16);
            *(uint2*)(Wsb + slab + t * 256 + ln * 4) = pk;
          }
        }
#pragma unroll
        for (int m = 8; m <= 32; m <<= 1)
#pragma unroll
          for (int b = 0; b < NB; ++b)
#pragma unroll
            for (int q = 0; q < 4; ++q)
              racc[b][q] += __shfl_xor(racc[b][q], m);
        if ((ln >> 3) == 0) {
          int r0 = (ln & 7) * 4;
#pragma unroll
          for (int b = 0; b < NB; ++b)
#pragma unroll
            for (int q = 0; q < 4; ++q) s_int[wv][b][r0 + q] = racc[b][q];
        }
      }
      // ---- influence[b,d] += sum_r inter[b,r] * Wt[i,j,r,d] ----
      if constexpr (MODE == 0) {
        const u16* tp = (const u16*)Wtv + slab;
#pragma unroll
        for (int t = 0; t < 16; ++t) {
          short8_t w8 = *(const short8_t*)(tp + t * 512 + ln * 8);
          int r = t * 2 + (ln >> 5);
          float v0 = s_int[wv][0][r], v1 = s_int[wv][1][r];
          float v2 = s_int[wv][2][r], v3 = s_int[wv][3][r];
#pragma unroll
          for (int q = 0; q < 8; ++q) {
            float wf = bf2f((u16)w8[q]);
            iacc[0][q] += v0 * wf;
            iacc[1][q] += v1 * wf;
            iacc[2][q] += v2 * wf;
            iacc[3][q] += v3 * wf;
          }
        }
      } else {
        const float* tp = (const float*)Wtv + slab;
#pragma unroll 8
        for (int t = 0; t < 32; ++t) {
          float4 w4 = *(const float4*)(tp + t * 256 + ln * 4);
          float v0 = s_int[wv][0][t], v1 = s_int[wv][1][t];
          float v2 = s_int[wv][2][t], v3 = s_int[wv][3][t];
          iacc[0][0] += v0 * w4.x; iacc[0][1] += v0 * w4.y;
          iacc[0][2] += v0 * w4.z; iacc[0][3] += v0 * w4.w;
          iacc[1][0] += v1 * w4.x; iacc[1][1] += v1 * w4.y;
          iacc[1][2] += v1 * w4.z; iacc[1][3] += v1 * w4.w;
          iacc[2][0] += v2 * w4.x; iacc[2][1] += v2 * w4.y;
          iacc[2][2] += v2 * w4.z; iacc[2][3] += v2 * w4.w;
          iacc[3][0] += v3 * w4.x; iacc[3][1] += v3 * w4.y;
          iacc[3][2] += v3 * w4.z; iacc[3][3] += v3 * w4.w;
          if constexpr (MODE == 1) {
            uint2 pk;
            pk.x = (unsigned)f2bf(w4.x) | ((unsigned)f2bf(w4.y) << 16);
            pk.y = (unsigned)f2bf(w4.z) | ((unsigned)f2bf(w4.w) << 16);
            *(uint2*)(Wtb + slab + t * 256 + ln * 4) = pk;
          }
        }
      }
    }
  }
  if constexpr (MODE == 0) {
#pragma unroll
    for (int b = 0; b < NB; ++b)
#pragma unroll
      for (int q = 0; q < 8; ++q) iacc[b][q] += __shfl_xor(iacc[b][q], 32);
    if (ln < 32) {
#pragma unroll
      for (int b = 0; b < NB; ++b)
#pragma unroll
        for (int q = 0; q < 8; ++q) s_acc[wv][b][ln * 8 + q] = iacc[b][q];
    }
  } else {
#pragma unroll
    for (int b = 0; b < NB; ++b)
#pragma unroll
      for (int q = 0; q < 4; ++q) s_acc[wv][b][ln * 4 + q] = iacc[b][q];
  }
  __syncthreads();
  int d = tid;
#pragma unroll
  for (int b = 0; b < NB; ++b) {
    float s = s_acc[0][b][d] + s_acc[1][b][d] + s_acc[2][b][d] + s_acc[3][b][d];
    part[(((size_t)ic * NB + b) * SL + j) * DM + d] = s;
  }
}

// ------- reduce partials + relu + residual + LayerNorm (per (b,j) row) ------
__global__ __launch_bounds__(256) void ln_k(float* __restrict__ Hs,
    const float* __restrict__ part, const float* __restrict__ g,
    const float* __restrict__ be, int last, u16* __restrict__ Hs_bf) {
  int j = blockIdx.x, b = blockIdx.y, d = threadIdx.x;
  size_t base = ((size_t)b * SL + j) * DM + d;
  float inf = 0.f;
#pragma unroll
  for (int icc = 0; icc < NCHUNK; ++icc)
    inf += part[(((size_t)icc * NB + b) * SL + j) * DM + d];
  float h = Hs[base] + fmaxf(inf, 0.f);
  float s1 = h, s2 = h * h;
#pragma unroll
  for (int m = 1; m < 64; m <<= 1) {
    s1 += __shfl_xor(s1, m);
    s2 += __shfl_xor(s2, m);
  }
  __shared__ float r1[4], r2[4];
  int wv = d >> 6;
  if ((d & 63) == 0) { r1[wv] = s1; r2[wv] = s2; }
  __syncthreads();
  s1 = r1[0] + r1[1] + r1[2] + r1[3];
  s2 = r2[0] + r2[1] + r2[2] + r2[3];
  float mu = s1 * (1.f / 256.f);
  float var = s2 * (1.f / 256.f) - mu * mu;
  float o = (h - mu) * rsqrtf(var + 1e-5f) * g[d] + be[d];
  Hs[base] = o;
  if (last) Hs_bf[base] = f2bf(o);
}

// ----------------- output expansion attention + Y (bf16) --------------------
__global__ __launch_bounds__(128) void attn_out_k(const float* __restrict__ Qo,
    const float* __restrict__ Kf, const float* __restrict__ Vf,
    u16* __restrict__ Ybf) {
  int bs = blockIdx.x, t = threadIdx.x;
  int b = bs >> 9;
  __shared__ float s_q[DM];
  __shared__ float s_p[SL];
  __shared__ float sred[2];
  s_q[t] = Qo[(size_t)bs * DM + t];
  s_q[t + 128] = Qo[(size_t)bs * DM + t + 128];
  __syncthreads();
  const float* kr = Kf + ((size_t)b * SL + t) * DM;
  float sc = 0.f;
#pragma unroll 8
  for (int d = 0; d < DM; ++d) sc += s_q[d] * kr[d];
  sc *= 0.0625f;
  float mx = sc;
#pragma unroll
  for (int m = 1; m < 64; m <<= 1) mx = fmaxf(mx, __shfl_xor(mx, m));
  if ((t & 63) == 0) sred[t >> 6] = mx;
  __syncthreads();
  mx = fmaxf(sred[0], sred[1]);
  float p = expf(sc - mx);
  float sum = p;
#pragma unroll
  for (int m = 1; m < 64; m <<= 1) sum += __shfl_xor(sum, m);
  __syncthreads();
  if ((t & 63) == 0) sred[t >> 6] = sum;
  __syncthreads();
  sum = sred[0] + sred[1];
  s_p[t] = p / sum;
  __syncthreads();
  for (int dd = t; dd < DM; dd += 128) {
    float y = 0.f;
    const float* vp = Vf + (size_t)b * SL * DM + dd;
#pragma unroll 8
    for (int k2 = 0; k2 < SL; ++k2) y += s_p[k2] * vp[(size_t)k2 * DM];
    Ybf[(size_t)bs * DM + dd] = f2bf(y);
  }
}

extern "C" void kernel_launch(void* const* d_in, const int* in_sizes, int n_in,
                              void* d_out, int out_size, void* d_ws,
                              size_t ws_size, hipStream_t stream) {
  (void)in_sizes; (void)n_in; (void)out_size;
  const int* ids = (const int*)d_in[0];
  const int* amask = (const int*)d_in[1];
  const float* tok = (const float*)d_in[2];
  const float* pos = (const float*)d_in[3];
  const float* Hsl = (const float*)d_in[4];
  const float* Ws = (const float*)d_in[5];
  const float* Wt = (const float*)d_in[6];
  const float* wq_in = (const float*)d_in[7];
  const float* wk_sl = (const float*)d_in[8];
  const float* wv_in = (const float*)d_in[9];
  const float* wq_out = (const float*)d_in[10];
  const float* wk_fin = (const float*)d_in[11];
  const float* wv_fin = (const float*)d_in[12];
  const float* w_out = (const float*)d_in[13];
  const float* lng = (const float*)d_in[14];
  const float* lnb = (const float*)d_in[15];

  char* base = (char*)d_ws;
  size_t used = 0;
  auto carve = [&](size_t bytes) {
    void* r = base + used;
    used += (bytes + 255) & ~(size_t)255;
    return r;
  };
  u16* x_bf = (u16*)carve((size_t)2048 * 256 * 2);
  float* Qi = (float*)carve((size_t)2048 * 256 * 4);
  float* Vi = (float*)carve((size_t)2048 * 256 * 4);
  float* Qo = (float*)carve((size_t)2048 * 256 * 4);
  float* Ksl = (float*)carve((size_t)128 * 256 * 4);
  float* Aat = (float*)carve((size_t)4 * 512 * 128 * 4);
  float* den = (float*)carve((size_t)512 * 4);
  float* Hst = (float*)carve((size_t)4 * 128 * 256 * 4);
  u16* Hs_bf = (u16*)carve((size_t)4 * 128 * 256 * 2);
  float* part = (float*)carve((size_t)16 * 4 * 128 * 256 * 4);
  float* Kf = (float*)carve((size_t)4 * 128 * 256 * 4);
  float* Vf = (float*)carve((size_t)4 * 128 * 256 * 4);
  u16* Ybf = (u16*)carve((size_t)2048 * 256 * 2);
  u16* Hbf = (u16*)carve((size_t)128 * 256 * 2);
  u16* wbf[6];
  for (int q = 0; q < 6; ++q) wbf[q] = (u16*)carve((size_t)256 * 256 * 2);
  u16* w_out_bf = (u16*)carve((size_t)32000 * 256 * 2);
  const size_t WN = (size_t)128 * 128 * 256 * 32;  // elems of each W tensor
  bool bigws = (used + 2 * WN * 2 + 512) <= ws_size;
  u16* Ws_bf = nullptr;
  u16* Wt_bf = nullptr;
  if (bigws) {
    Ws_bf = (u16*)carve(WN * 2);
    Wt_bf = (u16*)carve(WN * 2);
  }

  auto cvt = [&](const float* in, u16* out, size_t n) {
    int n4 = (int)(n / 4);
    int blocks = (n4 + 255) / 256;
    if (blocks > 2048) blocks = 2048;
    cvt_k<<<blocks, 256, 0, stream>>>(in, out, n4);
  };

  const float* sqw[6] = {wq_in, wk_sl, wv_in, wq_out, wk_fin, wv_fin};
  for (int q = 0; q < 6; ++q) cvt(sqw[q], wbf[q], 256 * 256);
  cvt(Hsl, Hbf, 128 * 256);
  cvt(w_out, w_out_bf, (size_t)32000 * 256);

  embed_k<<<2048, 256, 0, stream>>>(ids, tok, pos, x_bf);
  gemm_nt<<<dim3(32, 4), 256, 0, stream>>>(x_bf, wbf[0], Qi, 256);
  gemm_nt<<<dim3(32, 4), 256, 0, stream>>>(x_bf, wbf[2], Vi, 256);
  gemm_nt<<<dim3(32, 4), 256, 0, stream>>>(x_bf, wbf[3], Qo, 256);
  gemm_nt<<<dim3(2, 4), 256, 0, stream>>>(Hbf, wbf[1], Ksl, 256);
  attn_in_k<<<2048, 128, 0, stream>>>(Qi, Ksl, amask, Aat);
  colsum_k<<<2, 256, 0, stream>>>(Aat, den);
  irhs_k<<<dim3(128, 4), 256, 0, stream>>>(Aat, Vi, den, Hsl, Hst);
  for (int step = 0; step < 6; ++step) {
    if (bigws) {
      if (step == 0)
        bilinear_k<1><<<dim3(SL, 16), 256, 0, stream>>>(Hst, Ws, Wt, Ws_bf,
                                                        Wt_bf, part);
      else
        bilinear_k<0><<<dim3(SL, 16), 256, 0, stream>>>(Hst, Ws_bf, Wt_bf,
                                                        nullptr, nullptr, part);
    } else {
      bilinear_k<2><<<dim3(SL, 16), 256, 0, stream>>>(Hst, Ws, Wt, nullptr,
                                                      nullptr, part);
    }
    ln_k<<<dim3(128, 4), 256, 0, stream>>>(Hst, part, lng + step * DM,
                                           lnb + step * DM, step == 5 ? 1 : 0,
                                           Hs_bf);
  }
  gemm_nt<<<dim3(8, 4), 256, 0, stream>>>(Hs_bf, wbf[4], Kf, 256);
  gemm_nt<<<dim3(8, 4), 256, 0, stream>>>(Hs_bf, wbf[5], Vf, 256);
  attn_out_k<<<2048, 128, 0, stream>>>(Qo, Kf, Vf, Ybf);
  gemm_nt<<<dim3(32, 500), 256, 0, stream>>>(Ybf, w_out_bf, (float*)d_out,
                                             32000);
}

// Round 5
// 1262.724 us; speedup vs baseline: 1.4381x; 1.0385x over previous
//
#include <hip/hip_runtime.h>

typedef unsigned short u16;
typedef short short8_t __attribute__((ext_vector_type(8)));
typedef float f32x4 __attribute__((ext_vector_type(4)));

#define SL 128
#define DM 256
#define RK 32
#define SEQ 512
#define NB 4
#define NCHUNK 32

__device__ __forceinline__ float bf2f(u16 u) {
  return __uint_as_float(((unsigned int)u) << 16);
}
__device__ __forceinline__ u16 f2bf(float f) {
  unsigned int x = __float_as_uint(f);
  x += 0x7fffu + ((x >> 16) & 1u);
  return (u16)(x >> 16);
}

// ----------------- f32 -> bf16 conversion (vectorized) ----------------------
__global__ __launch_bounds__(256) void cvt_k(const float* __restrict__ in,
                                             u16* __restrict__ out, int n4) {
  for (int i = blockIdx.x * blockDim.x + threadIdx.x; i < n4;
       i += gridDim.x * blockDim.x) {
    float4 v = ((const float4*)in)[i];
    u16 o0 = f2bf(v.x), o1 = f2bf(v.y), o2 = f2bf(v.z), o3 = f2bf(v.w);
    unsigned int lo = (unsigned int)o0 | ((unsigned int)o1 << 16);
    unsigned int hi = (unsigned int)o2 | ((unsigned int)o3 << 16);
    ((uint2*)out)[i] = make_uint2(lo, hi);
  }
}

// ---------------- embedding: x = tok[id] + pos[s] (bf16 out) ----------------
__global__ __launch_bounds__(256) void embed_k(const int* __restrict__ ids,
    const float* __restrict__ tok, const float* __restrict__ pos,
    u16* __restrict__ xbf) {
  int bs = blockIdx.x, d = threadIdx.x;
  int id = ids[bs];
  int s = bs & (SEQ - 1);
  float v = tok[(size_t)id * DM + d] + pos[(size_t)s * DM + d];
  xbf[(size_t)bs * DM + d] = f2bf(v);
}

// ------------- generic NT GEMM: C[M,N] = A[M,256] * B[N,256]^T --------------
__global__ __launch_bounds__(256) void gemm_nt(const u16* __restrict__ A,
    const u16* __restrict__ Bw, float* __restrict__ Cout, int N) {
  __shared__ u16 s_a[64 * 256];
  __shared__ u16 s_b[64 * 256];
  int tid = threadIdx.x;
  int m0 = blockIdx.x * 64, n0 = blockIdx.y * 64;
  for (int c = tid; c < 2048; c += 256) {
    int row = c >> 5;
    int ec = (c & 31) << 3;
    short8_t va = *(const short8_t*)(A + (size_t)(m0 + row) * 256 + ec);
    short8_t vb = *(const short8_t*)(Bw + (size_t)(n0 + row) * 256 + ec);
    int sw = ec ^ ((row & 7) << 3);
    *(short8_t*)(&s_a[row * 256 + sw]) = va;
    *(short8_t*)(&s_b[row * 256 + sw]) = vb;
  }
  __syncthreads();
  int lane = tid & 63;
  int w = tid >> 6;
  int wm = (w >> 1) * 32, wn = (w & 1) * 32;
  int lr = lane & 15, lk = (lane >> 4) << 3;
  f32x4 acc00 = {0.f, 0.f, 0.f, 0.f};
  f32x4 acc01 = {0.f, 0.f, 0.f, 0.f};
  f32x4 acc10 = {0.f, 0.f, 0.f, 0.f};
  f32x4 acc11 = {0.f, 0.f, 0.f, 0.f};
#pragma unroll
  for (int ks = 0; ks < 8; ++ks) {
    int ke = ks * 32 + lk;
    int r0 = wm + lr, r1 = wm + 16 + lr;
    int c0 = wn + lr, c1 = wn + 16 + lr;
    short8_t a0 = *(const short8_t*)(&s_a[r0 * 256 + (ke ^ ((r0 & 7) << 3))]);
    short8_t a1 = *(const short8_t*)(&s_a[r1 * 256 + (ke ^ ((r1 & 7) << 3))]);
    short8_t b0 = *(const short8_t*)(&s_b[c0 * 256 + (ke ^ ((c0 & 7) << 3))]);
    short8_t b1 = *(const short8_t*)(&s_b[c1 * 256 + (ke ^ ((c1 & 7) << 3))]);
    acc00 = __builtin_amdgcn_mfma_f32_16x16x32_bf16(a0, b0, acc00, 0, 0, 0);
    acc01 = __builtin_amdgcn_mfma_f32_16x16x32_bf16(a0, b1, acc01, 0, 0, 0);
    acc10 = __builtin_amdgcn_mfma_f32_16x16x32_bf16(a1, b0, acc10, 0, 0, 0);
    acc11 = __builtin_amdgcn_mfma_f32_16x16x32_bf16(a1, b1, acc11, 0, 0, 0);
  }
  int rbase = (lane >> 4) << 2;
#pragma unroll
  for (int i = 0; i < 2; ++i) {
#pragma unroll
    for (int jj = 0; jj < 2; ++jj) {
      f32x4 v = (i == 0) ? (jj == 0 ? acc00 : acc01)
                         : (jj == 0 ? acc10 : acc11);
      int row0 = m0 + wm + i * 16 + rbase;
      int col = n0 + wn + jj * 16 + lr;
#pragma unroll
      for (int q = 0; q < 4; ++q)
        Cout[(size_t)(row0 + q) * (size_t)N + col] = v[q];
    }
  }
}

// ------- input compression attention: softmax over slots, then mask ---------
__global__ __launch_bounds__(128) void attn_in_k(const float* __restrict__ Qi,
    const float* __restrict__ Ksl, const int* __restrict__ am,
    float* __restrict__ Aout) {
  int bs = blockIdx.x, t = threadIdx.x;
  __shared__ float s_q[DM];
  __shared__ float sred[2];
  s_q[t] = Qi[(size_t)bs * DM + t];
  s_q[t + 128] = Qi[(size_t)bs * DM + t + 128];
  __syncthreads();
  const float* kr = Ksl + (size_t)t * DM;
  float sc = 0.f;
#pragma unroll 8
  for (int d = 0; d < DM; ++d) sc += s_q[d] * kr[d];
  sc *= 0.0625f;
  float mx = sc;
#pragma unroll
  for (int m = 1; m < 64; m <<= 1) mx = fmaxf(mx, __shfl_xor(mx, m));
  if ((t & 63) == 0) sred[t >> 6] = mx;
  __syncthreads();
  mx = fmaxf(sred[0], sred[1]);
  float p = expf(sc - mx);
  float sum = p;
#pragma unroll
  for (int m = 1; m < 64; m <<= 1) sum += __shfl_xor(sum, m);
  __syncthreads();
  if ((t & 63) == 0) sred[t >> 6] = sum;
  __syncthreads();
  sum = sred[0] + sred[1];
  p = (p / sum) * (float)am[bs];
  Aout[(size_t)bs * SL + t] = p;
}

// --------- column sums over s: den[b,k] = sum_s A[b,s,k] + 1e-8 -------------
__global__ void colsum_k(const float* __restrict__ A, float* __restrict__ den) {
  int t = blockIdx.x * blockDim.x + threadIdx.x;
  if (t >= NB * SL) return;
  int b = t >> 7, k = t & (SL - 1);
  const float* ap = A + (size_t)b * SEQ * SL + k;
  float s = 0.f;
#pragma unroll 4
  for (int si = 0; si < SEQ; ++si) s += ap[(size_t)si * SL];
  den[t] = s + 1e-8f;
}

// ------ IR[b,k,d] = sum_s A[b,s,k]*Vi[b,s,d] / den;  Hs = H + IR ------------
__global__ __launch_bounds__(256) void irhs_k(const float* __restrict__ A,
    const float* __restrict__ Vi, const float* __restrict__ den,
    const float* __restrict__ H, float* __restrict__ Hs) {
  int k = blockIdx.x, b = blockIdx.y, d = threadIdx.x;
  const float* ap = A + (size_t)b * SEQ * SL + k;
  const float* vp = Vi + (size_t)b * SEQ * DM + d;
  float s = 0.f;
#pragma unroll 4
  for (int si = 0; si < SEQ; ++si)
    s += ap[(size_t)si * SL] * vp[(size_t)si * DM];
  float inv = 1.f / den[b * SL + k];
  Hs[((size_t)b * SL + k) * DM + d] = H[(size_t)k * DM + d] + s * inv;
}

// -------------------- bilinear all-pairs slot mixing ------------------------
// ONE pair (i,j) per wave; block (j, ic) = 4 waves covering i in [4ic,4ic+4).
// All W loads register-prefetched before compute so the shfl-reduce latency
// overlaps memory latency. MODE 0: bf16 W. MODE 1: f32 W + write bf16 slabs.
// MODE 2: f32 W, no write.
template <int MODE>
__global__ __launch_bounds__(256, 2) void bilinear_k(
    const float* __restrict__ Hs, const void* __restrict__ Wsv,
    const void* __restrict__ Wtv, u16* __restrict__ Wsb,
    u16* __restrict__ Wtb, float* __restrict__ part) {
  constexpr int QN = (MODE == 0) ? 8 : 4;
  int j = blockIdx.x, ic = blockIdx.y, tid = threadIdx.x;
  int wv = tid >> 6, ln = tid & 63;
  __shared__ float s_hs[NB][4][DM];   // 16 KB
  __shared__ float s_int[4][NB][RK];  // 2 KB, per-wave slot
  __shared__ float s_acc[4][NB][DM];  // 16 KB, per-wave slot
  int i0 = ic * 4;
  for (int c = tid; c < (NB * 4 * DM) / 4; c += 256) {
    int fi = c * 4;
    int b = fi >> 10, rest = fi & 1023;
    *(float4*)(&s_hs[0][0][0] + fi) =
        *(const float4*)(Hs + (size_t)b * SL * DM + (size_t)i0 * DM + rest);
  }
  __syncthreads();
  int il = wv;
  int i = i0 + il;
  float iacc[NB][QN];
#pragma unroll
  for (int b = 0; b < NB; ++b)
#pragma unroll
    for (int q = 0; q < QN; ++q) iacc[b][q] = 0.f;
  if (i != j) {
    size_t slab = (size_t)(i * SL + j) * (DM * RK);
    if constexpr (MODE == 0) {
      const u16* wp = (const u16*)Wsv + slab;
      const u16* tp = (const u16*)Wtv + slab;
      short8_t wsr[16], wtr[16];
#pragma unroll
      for (int t = 0; t < 16; ++t)
        wsr[t] = *(const short8_t*)(wp + t * 512 + ln * 8);
#pragma unroll
      for (int t = 0; t < 16; ++t)
        wtr[t] = *(const short8_t*)(tp + t * 512 + ln * 8);
      float racc[NB][8];
#pragma unroll
      for (int b = 0; b < NB; ++b)
#pragma unroll
        for (int q = 0; q < 8; ++q) racc[b][q] = 0.f;
#pragma unroll
      for (int t = 0; t < 16; ++t) {
        int d = t * 16 + (ln >> 2);
        float h0 = s_hs[0][il][d], h1 = s_hs[1][il][d];
        float h2 = s_hs[2][il][d], h3 = s_hs[3][il][d];
#pragma unroll
        for (int q = 0; q < 8; ++q) {
          float wf = bf2f((u16)wsr[t][q]);
          racc[0][q] += h0 * wf;
          racc[1][q] += h1 * wf;
          racc[2][q] += h2 * wf;
          racc[3][q] += h3 * wf;
        }
      }
#pragma unroll
      for (int m = 4; m <= 32; m <<= 1)
#pragma unroll
        for (int b = 0; b < NB; ++b)
#pragma unroll
          for (int q = 0; q < 8; ++q) racc[b][q] += __shfl_xor(racc[b][q], m);
      if ((ln >> 2) == 0) {
        int r0 = (ln & 3) * 8;
#pragma unroll
        for (int b = 0; b < NB; ++b)
#pragma unroll
          for (int q = 0; q < 8; ++q) s_int[wv][b][r0 + q] = racc[b][q];
      }
      // same-wave LDS write->read: in-order, no barrier needed
#pragma unroll
      for (int t = 0; t < 16; ++t) {
        int r = t * 2 + (ln >> 5);
        float v0 = s_int[wv][0][r], v1 = s_int[wv][1][r];
        float v2 = s_int[wv][2][r], v3 = s_int[wv][3][r];
#pragma unroll
        for (int q = 0; q < 8; ++q) {
          float wf = bf2f((u16)wtr[t][q]);
          iacc[0][q] += v0 * wf;
          iacc[1][q] += v1 * wf;
          iacc[2][q] += v2 * wf;
          iacc[3][q] += v3 * wf;
        }
      }
    } else {
      const float* wp = (const float*)Wsv + slab;
      const float* tp = (const float*)Wtv + slab;
      float4 wsr[32];
#pragma unroll
      for (int t = 0; t < 32; ++t)
        wsr[t] = *(const float4*)(wp + t * 256 + ln * 4);
      float racc[NB][4];
#pragma unroll
      for (int b = 0; b < NB; ++b)
#pragma unroll
        for (int q = 0; q < 4; ++q) racc[b][q] = 0.f;
#pragma unroll
      for (int t = 0; t < 32; ++t) {
        float4 w4 = wsr[t];
        int d = t * 8 + (ln >> 3);
        float h0 = s_hs[0][il][d], h1 = s_hs[1][il][d];
        float h2 = s_hs[2][il][d], h3 = s_hs[3][il][d];
        racc[0][0] += h0 * w4.x; racc[0][1] += h0 * w4.y;
        racc[0][2] += h0 * w4.z; racc[0][3] += h0 * w4.w;
        racc[1][0] += h1 * w4.x; racc[1][1] += h1 * w4.y;
        racc[1][2] += h1 * w4.z; racc[1][3] += h1 * w4.w;
        racc[2][0] += h2 * w4.x; racc[2][1] += h2 * w4.y;
        racc[2][2] += h2 * w4.z; racc[2][3] += h2 * w4.w;
        racc[3][0] += h3 * w4.x; racc[3][1] += h3 * w4.y;
        racc[3][2] += h3 * w4.z; racc[3][3] += h3 * w4.w;
        if constexpr (MODE == 1) {
          uint2 pk;
          pk.x = (unsigned)f2bf(w4.x) | ((unsigned)f2bf(w4.y) << 16);
          pk.y = (unsigned)f2bf(w4.z) | ((unsigned)f2bf(w4.w) << 16);
          *(uint2*)(Wsb + slab + t * 256 + ln * 4) = pk;
        }
      }
#pragma unroll
      for (int m = 8; m <= 32; m <<= 1)
#pragma unroll
        for (int b = 0; b < NB; ++b)
#pragma unroll
          for (int q = 0; q < 4; ++q) racc[b][q] += __shfl_xor(racc[b][q], m);
      if ((ln >> 3) == 0) {
        int r0 = (ln & 7) * 4;
#pragma unroll
        for (int b = 0; b < NB; ++b)
#pragma unroll
          for (int q = 0; q < 4; ++q) s_int[wv][b][r0 + q] = racc[b][q];
      }
#pragma unroll
      for (int c8 = 0; c8 < 4; ++c8) {
        float4 wtr[8];
#pragma unroll
        for (int t = 0; t < 8; ++t)
          wtr[t] = *(const float4*)(tp + (c8 * 8 + t) * 256 + ln * 4);
#pragma unroll
        for (int t = 0; t < 8; ++t) {
          int r = c8 * 8 + t;
          float4 w4 = wtr[t];
          float v0 = s_int[wv][0][r], v1 = s_int[wv][1][r];
          float v2 = s_int[wv][2][r], v3 = s_int[wv][3][r];
          iacc[0][0] += v0 * w4.x; iacc[0][1] += v0 * w4.y;
          iacc[0][2] += v0 * w4.z; iacc[0][3] += v0 * w4.w;
          iacc[1][0] += v1 * w4.x; iacc[1][1] += v1 * w4.y;
          iacc[1][2] += v1 * w4.z; iacc[1][3] += v1 * w4.w;
          iacc[2][0] += v2 * w4.x; iacc[2][1] += v2 * w4.y;
          iacc[2][2] += v2 * w4.z; iacc[2][3] += v2 * w4.w;
          iacc[3][0] += v3 * w4.x; iacc[3][1] += v3 * w4.y;
          iacc[3][2] += v3 * w4.z; iacc[3][3] += v3 * w4.w;
          if constexpr (MODE == 1) {
            uint2 pk;
            pk.x = (unsigned)f2bf(w4.x) | ((unsigned)f2bf(w4.y) << 16);
            pk.y = (unsigned)f2bf(w4.z) | ((unsigned)f2bf(w4.w) << 16);
            *(uint2*)(Wtb + slab + r * 256 + ln * 4) = pk;
          }
        }
      }
    }
  }
  if constexpr (MODE == 0) {
#pragma unroll
    for (int b = 0; b < NB; ++b)
#pragma unroll
      for (int q = 0; q < 8; ++q) iacc[b][q] += __shfl_xor(iacc[b][q], 32);
    if (ln < 32) {
#pragma unroll
      for (int b = 0; b < NB; ++b)
#pragma unroll
        for (int q = 0; q < 8; ++q) s_acc[wv][b][ln * 8 + q] = iacc[b][q];
    }
  } else {
#pragma unroll
    for (int b = 0; b < NB; ++b)
#pragma unroll
      for (int q = 0; q < 4; ++q) s_acc[wv][b][ln * 4 + q] = iacc[b][q];
  }
  __syncthreads();
  for (int c = tid; c < NB * DM; c += 256) {
    int b = c >> 8, d = c & 255;
    float s = s_acc[0][b][d] + s_acc[1][b][d] + s_acc[2][b][d] + s_acc[3][b][d];
    part[(((size_t)ic * NB + b) * SL + j) * DM + d] = s;
  }
}

// ------- reduce partials + relu + residual + LayerNorm (per (b,j) row) ------
__global__ __launch_bounds__(256) void ln_k(float* __restrict__ Hs,
    const float* __restrict__ part, const float* __restrict__ g,
    const float* __restrict__ be, int last, u16* __restrict__ Hs_bf) {
  int j = blockIdx.x, b = blockIdx.y, d = threadIdx.x;
  size_t base = ((size_t)b * SL + j) * DM + d;
  float inf = 0.f;
#pragma unroll
  for (int icc = 0; icc < NCHUNK; ++icc)
    inf += part[(((size_t)icc * NB + b) * SL + j) * DM + d];
  float h = Hs[base] + fmaxf(inf, 0.f);
  float s1 = h, s2 = h * h;
#pragma unroll
  for (int m = 1; m < 64; m <<= 1) {
    s1 += __shfl_xor(s1, m);
    s2 += __shfl_xor(s2, m);
  }
  __shared__ float r1[4], r2[4];
  int wv = d >> 6;
  if ((d & 63) == 0) { r1[wv] = s1; r2[wv] = s2; }
  __syncthreads();
  s1 = r1[0] + r1[1] + r1[2] + r1[3];
  s2 = r2[0] + r2[1] + r2[2] + r2[3];
  float mu = s1 * (1.f / 256.f);
  float var = s2 * (1.f / 256.f) - mu * mu;
  float o = (h - mu) * rsqrtf(var + 1e-5f) * g[d] + be[d];
  Hs[base] = o;
  if (last) Hs_bf[base] = f2bf(o);
}

// ----------------- output expansion attention + Y (bf16) --------------------
__global__ __launch_bounds__(128) void attn_out_k(const float* __restrict__ Qo,
    const float* __restrict__ Kf, const float* __restrict__ Vf,
    u16* __restrict__ Ybf) {
  int bs = blockIdx.x, t = threadIdx.x;
  int b = bs >> 9;
  __shared__ float s_q[DM];
  __shared__ float s_p[SL];
  __shared__ float sred[2];
  s_q[t] = Qo[(size_t)bs * DM + t];
  s_q[t + 128] = Qo[(size_t)bs * DM + t + 128];
  __syncthreads();
  const float* kr = Kf + ((size_t)b * SL + t) * DM;
  float sc = 0.f;
#pragma unroll 8
  for (int d = 0; d < DM; ++d) sc += s_q[d] * kr[d];
  sc *= 0.0625f;
  float mx = sc;
#pragma unroll
  for (int m = 1; m < 64; m <<= 1) mx = fmaxf(mx, __shfl_xor(mx, m));
  if ((t & 63) == 0) sred[t >> 6] = mx;
  __syncthreads();
  mx = fmaxf(sred[0], sred[1]);
  float p = expf(sc - mx);
  float sum = p;
#pragma unroll
  for (int m = 1; m < 64; m <<= 1) sum += __shfl_xor(sum, m);
  __syncthreads();
  if ((t & 63) == 0) sred[t >> 6] = sum;
  __syncthreads();
  sum = sred[0] + sred[1];
  s_p[t] = p / sum;
  __syncthreads();
  for (int dd = t; dd < DM; dd += 128) {
    float y = 0.f;
    const float* vp = Vf + (size_t)b * SL * DM + dd;
#pragma unroll 8
    for (int k2 = 0; k2 < SL; ++k2) y += s_p[k2] * vp[(size_t)k2 * DM];
    Ybf[(size_t)bs * DM + dd] = f2bf(y);
  }
}

extern "C" void kernel_launch(void* const* d_in, const int* in_sizes, int n_in,
                              void* d_out, int out_size, void* d_ws,
                              size_t ws_size, hipStream_t stream) {
  (void)in_sizes; (void)n_in; (void)out_size;
  const int* ids = (const int*)d_in[0];
  const int* amask = (const int*)d_in[1];
  const float* tok = (const float*)d_in[2];
  const float* pos = (const float*)d_in[3];
  const float* Hsl = (const float*)d_in[4];
  const float* Ws = (const float*)d_in[5];
  const float* Wt = (const float*)d_in[6];
  const float* wq_in = (const float*)d_in[7];
  const float* wk_sl = (const float*)d_in[8];
  const float* wv_in = (const float*)d_in[9];
  const float* wq_out = (const float*)d_in[10];
  const float* wk_fin = (const float*)d_in[11];
  const float* wv_fin = (const float*)d_in[12];
  const float* w_out = (const float*)d_in[13];
  const float* lng = (const float*)d_in[14];
  const float* lnb = (const float*)d_in[15];

  char* base = (char*)d_ws;
  size_t used = 0;
  auto carve = [&](size_t bytes) {
    void* r = base + used;
    used += (bytes + 255) & ~(size_t)255;
    return r;
  };
  u16* x_bf = (u16*)carve((size_t)2048 * 256 * 2);
  float* Qi = (float*)carve((size_t)2048 * 256 * 4);
  float* Vi = (float*)carve((size_t)2048 * 256 * 4);
  float* Qo = (float*)carve((size_t)2048 * 256 * 4);
  float* Ksl = (float*)carve((size_t)128 * 256 * 4);
  float* Aat = (float*)carve((size_t)4 * 512 * 128 * 4);
  float* den = (float*)carve((size_t)512 * 4);
  float* Hst = (float*)carve((size_t)4 * 128 * 256 * 4);
  u16* Hs_bf = (u16*)carve((size_t)4 * 128 * 256 * 2);
  float* part = (float*)carve((size_t)NCHUNK * 4 * 128 * 256 * 4);
  float* Kf = (float*)carve((size_t)4 * 128 * 256 * 4);
  float* Vf = (float*)carve((size_t)4 * 128 * 256 * 4);
  u16* Ybf = (u16*)carve((size_t)2048 * 256 * 2);
  u16* Hbf = (u16*)carve((size_t)128 * 256 * 2);
  u16* wbf[6];
  for (int q = 0; q < 6; ++q) wbf[q] = (u16*)carve((size_t)256 * 256 * 2);
  u16* w_out_bf = (u16*)carve((size_t)32000 * 256 * 2);
  const size_t WN = (size_t)128 * 128 * 256 * 32;  // elems of each W tensor
  bool bigws = (used + 2 * WN * 2 + 512) <= ws_size;
  u16* Ws_bf = nullptr;
  u16* Wt_bf = nullptr;
  if (bigws) {
    Ws_bf = (u16*)carve(WN * 2);
    Wt_bf = (u16*)carve(WN * 2);
  }

  auto cvt = [&](const float* in, u16* out, size_t n) {
    int n4 = (int)(n / 4);
    int blocks = (n4 + 255) / 256;
    if (blocks > 2048) blocks = 2048;
    cvt_k<<<blocks, 256, 0, stream>>>(in, out, n4);
  };

  const float* sqw[6] = {wq_in, wk_sl, wv_in, wq_out, wk_fin, wv_fin};
  for (int q = 0; q < 6; ++q) cvt(sqw[q], wbf[q], 256 * 256);
  cvt(Hsl, Hbf, 128 * 256);
  cvt(w_out, w_out_bf, (size_t)32000 * 256);

  embed_k<<<2048, 256, 0, stream>>>(ids, tok, pos, x_bf);
  gemm_nt<<<dim3(32, 4), 256, 0, stream>>>(x_bf, wbf[0], Qi, 256);
  gemm_nt<<<dim3(32, 4), 256, 0, stream>>>(x_bf, wbf[2], Vi, 256);
  gemm_nt<<<dim3(32, 4), 256, 0, stream>>>(x_bf, wbf[3], Qo, 256);
  gemm_nt<<<dim3(2, 4), 256, 0, stream>>>(Hbf, wbf[1], Ksl, 256);
  attn_in_k<<<2048, 128, 0, stream>>>(Qi, Ksl, amask, Aat);
  colsum_k<<<2, 256, 0, stream>>>(Aat, den);
  irhs_k<<<dim3(128, 4), 256, 0, stream>>>(Aat, Vi, den, Hsl, Hst);
  for (int step = 0; step < 6; ++step) {
    if (bigws) {
      if (step == 0)
        bilinear_k<1><<<dim3(SL, 32), 256, 0, stream>>>(Hst, Ws, Wt, Ws_bf,
                                                        Wt_bf, part);
      else
        bilinear_k<0><<<dim3(SL, 32), 256, 0, stream>>>(Hst, Ws_bf, Wt_bf,
                                                        nullptr, nullptr, part);
    } else {
      bilinear_k<2><<<dim3(SL, 32), 256, 0, stream>>>(Hst, Ws, Wt, nullptr,
                                                      nullptr, part);
    }
    ln_k<<<dim3(128, 4), 256, 0, stream>>>(Hst, part, lng + step * DM,
                                           lnb + step * DM, step == 5 ? 1 : 0,
                                           Hs_bf);
  }
  gemm_nt<<<dim3(8, 4), 256, 0, stream>>>(Hs_bf, wbf[4], Kf, 256);
  gemm_nt<<<dim3(8, 4), 256, 0, stream>>>(Hs_bf, wbf[5], Vf, 256);
  attn_out_k<<<2048, 128, 0, stream>>>(Qo, Kf, Vf, Ybf);
  gemm_nt<<<dim3(32, 500), 256, 0, stream>>>(Ybf, w_out_bf, (float*)d_out,
                                             32000);
}

// Round 6
// 1009.509 us; speedup vs baseline: 1.7988x; 1.2508x over previous
//
#include <hip/hip_runtime.h>

typedef unsigned short u16;
typedef unsigned long long u64;
typedef short short8_t __attribute__((ext_vector_type(8)));
typedef float f32x4 __attribute__((ext_vector_type(4)));

#define SL 128
#define DM 256
#define RK 32
#define SEQ 512
#define NB 4
#define NCHUNK 32

__device__ __forceinline__ float bf2f(u16 u) {
  return __uint_as_float(((unsigned int)u) << 16);
}
__device__ __forceinline__ u16 f2bf(float f) {
  unsigned int x = __float_as_uint(f);
  x += 0x7fffu + ((x >> 16) & 1u);
  return (u16)(x >> 16);
}

// ----------------- f32 -> bf16 conversion (vectorized) ----------------------
__global__ __launch_bounds__(256) void cvt_k(const float* __restrict__ in,
                                             u16* __restrict__ out, int n4) {
  for (int i = blockIdx.x * blockDim.x + threadIdx.x; i < n4;
       i += gridDim.x * blockDim.x) {
    float4 v = ((const float4*)in)[i];
    u16 o0 = f2bf(v.x), o1 = f2bf(v.y), o2 = f2bf(v.z), o3 = f2bf(v.w);
    unsigned int lo = (unsigned int)o0 | ((unsigned int)o1 << 16);
    unsigned int hi = (unsigned int)o2 | ((unsigned int)o3 << 16);
    ((uint2*)out)[i] = make_uint2(lo, hi);
  }
}

// ------- batched small cvt: 6 square weights (64K elems) + H (32K) ---------
struct CvtJobs { const float* src[7]; };
__global__ __launch_bounds__(256) void cvt_all_k(CvtJobs jobs,
    u16* __restrict__ wbase, u16* __restrict__ Hbf) {
  int z = blockIdx.y;
  const float* in = jobs.src[z];
  u16* out = (z < 6) ? (wbase + (size_t)z * 65536) : Hbf;
  int n4 = (z < 6) ? 16384 : 8192;
  for (int i = blockIdx.x * 256 + threadIdx.x; i < n4; i += gridDim.x * 256) {
    float4 v = ((const float4*)in)[i];
    unsigned int lo = (unsigned)f2bf(v.x) | ((unsigned)f2bf(v.y) << 16);
    unsigned int hi = (unsigned)f2bf(v.z) | ((unsigned)f2bf(v.w) << 16);
    ((uint2*)out)[i] = make_uint2(lo, hi);
  }
}

// ---------------- embedding: x = tok[id] + pos[s] (bf16 out) ----------------
__global__ __launch_bounds__(256) void embed_k(const int* __restrict__ ids,
    const float* __restrict__ tok, const float* __restrict__ pos,
    u16* __restrict__ xbf) {
  int bs = blockIdx.x, d = threadIdx.x;
  int id = ids[bs];
  int s = bs & (SEQ - 1);
  float v = tok[(size_t)id * DM + d] + pos[(size_t)s * DM + d];
  xbf[(size_t)bs * DM + d] = f2bf(v);
}

// ------------- generic NT GEMM: C[M,N] = A[M,256] * B[N,256]^T --------------
__global__ __launch_bounds__(256) void gemm_nt(const u16* __restrict__ A,
    const u16* __restrict__ Bw, float* __restrict__ Cout, int N) {
  __shared__ u16 s_a[64 * 256];
  __shared__ u16 s_b[64 * 256];
  int tid = threadIdx.x;
  int m0 = blockIdx.x * 64, n0 = blockIdx.y * 64;
  for (int c = tid; c < 2048; c += 256) {
    int row = c >> 5;
    int ec = (c & 31) << 3;
    short8_t va = *(const short8_t*)(A + (size_t)(m0 + row) * 256 + ec);
    short8_t vb = *(const short8_t*)(Bw + (size_t)(n0 + row) * 256 + ec);
    int sw = ec ^ ((row & 7) << 3);
    *(short8_t*)(&s_a[row * 256 + sw]) = va;
    *(short8_t*)(&s_b[row * 256 + sw]) = vb;
  }
  __syncthreads();
  int lane = tid & 63;
  int w = tid >> 6;
  int wm = (w >> 1) * 32, wn = (w & 1) * 32;
  int lr = lane & 15, lk = (lane >> 4) << 3;
  f32x4 acc00 = {0.f, 0.f, 0.f, 0.f};
  f32x4 acc01 = {0.f, 0.f, 0.f, 0.f};
  f32x4 acc10 = {0.f, 0.f, 0.f, 0.f};
  f32x4 acc11 = {0.f, 0.f, 0.f, 0.f};
#pragma unroll
  for (int ks = 0; ks < 8; ++ks) {
    int ke = ks * 32 + lk;
    int r0 = wm + lr, r1 = wm + 16 + lr;
    int c0 = wn + lr, c1 = wn + 16 + lr;
    short8_t a0 = *(const short8_t*)(&s_a[r0 * 256 + (ke ^ ((r0 & 7) << 3))]);
    short8_t a1 = *(const short8_t*)(&s_a[r1 * 256 + (ke ^ ((r1 & 7) << 3))]);
    short8_t b0 = *(const short8_t*)(&s_b[c0 * 256 + (ke ^ ((c0 & 7) << 3))]);
    short8_t b1 = *(const short8_t*)(&s_b[c1 * 256 + (ke ^ ((c1 & 7) << 3))]);
    acc00 = __builtin_amdgcn_mfma_f32_16x16x32_bf16(a0, b0, acc00, 0, 0, 0);
    acc01 = __builtin_amdgcn_mfma_f32_16x16x32_bf16(a0, b1, acc01, 0, 0, 0);
    acc10 = __builtin_amdgcn_mfma_f32_16x16x32_bf16(a1, b0, acc10, 0, 0, 0);
    acc11 = __builtin_amdgcn_mfma_f32_16x16x32_bf16(a1, b1, acc11, 0, 0, 0);
  }
  int rbase = (lane >> 4) << 2;
#pragma unroll
  for (int i = 0; i < 2; ++i) {
#pragma unroll
    for (int jj = 0; jj < 2; ++jj) {
      f32x4 v = (i == 0) ? (jj == 0 ? acc00 : acc01)
                         : (jj == 0 ? acc10 : acc11);
      int row0 = m0 + wm + i * 16 + rbase;
      int col = n0 + wn + jj * 16 + lr;
#pragma unroll
      for (int q = 0; q < 4; ++q)
        Cout[(size_t)(row0 + q) * (size_t)N + col] = v[q];
    }
  }
}

// ---- z-batched NT GEMM (N=256): B = wbase + qsel(z)*64K, C = Cb + z*cs -----
__global__ __launch_bounds__(256) void gemm_nt3(const u16* __restrict__ A,
    const u16* __restrict__ wbase, float* __restrict__ Cbase, int q0, int q1,
    int q2, size_t cstride) {
  int z = blockIdx.z;
  int q = (z == 0) ? q0 : ((z == 1) ? q1 : q2);
  const u16* Bw = wbase + (size_t)q * 65536;
  float* Cout = Cbase + (size_t)z * cstride;
  __shared__ u16 s_a[64 * 256];
  __shared__ u16 s_b[64 * 256];
  int tid = threadIdx.x;
  int m0 = blockIdx.x * 64, n0 = blockIdx.y * 64;
  for (int c = tid; c < 2048; c += 256) {
    int row = c >> 5;
    int ec = (c & 31) << 3;
    short8_t va = *(const short8_t*)(A + (size_t)(m0 + row) * 256 + ec);
    short8_t vb = *(const short8_t*)(Bw + (size_t)(n0 + row) * 256 + ec);
    int sw = ec ^ ((row & 7) << 3);
    *(short8_t*)(&s_a[row * 256 + sw]) = va;
    *(short8_t*)(&s_b[row * 256 + sw]) = vb;
  }
  __syncthreads();
  int lane = tid & 63;
  int w = tid >> 6;
  int wm = (w >> 1) * 32, wn = (w & 1) * 32;
  int lr = lane & 15, lk = (lane >> 4) << 3;
  f32x4 acc00 = {0.f, 0.f, 0.f, 0.f};
  f32x4 acc01 = {0.f, 0.f, 0.f, 0.f};
  f32x4 acc10 = {0.f, 0.f, 0.f, 0.f};
  f32x4 acc11 = {0.f, 0.f, 0.f, 0.f};
#pragma unroll
  for (int ks = 0; ks < 8; ++ks) {
    int ke = ks * 32 + lk;
    int r0 = wm + lr, r1 = wm + 16 + lr;
    int c0 = wn + lr, c1 = wn + 16 + lr;
    short8_t a0 = *(const short8_t*)(&s_a[r0 * 256 + (ke ^ ((r0 & 7) << 3))]);
    short8_t a1 = *(const short8_t*)(&s_a[r1 * 256 + (ke ^ ((r1 & 7) << 3))]);
    short8_t b0 = *(const short8_t*)(&s_b[c0 * 256 + (ke ^ ((c0 & 7) << 3))]);
    short8_t b1 = *(const short8_t*)(&s_b[c1 * 256 + (ke ^ ((c1 & 7) << 3))]);
    acc00 = __builtin_amdgcn_mfma_f32_16x16x32_bf16(a0, b0, acc00, 0, 0, 0);
    acc01 = __builtin_amdgcn_mfma_f32_16x16x32_bf16(a0, b1, acc01, 0, 0, 0);
    acc10 = __builtin_amdgcn_mfma_f32_16x16x32_bf16(a1, b0, acc10, 0, 0, 0);
    acc11 = __builtin_amdgcn_mfma_f32_16x16x32_bf16(a1, b1, acc11, 0, 0, 0);
  }
  int rbase = (lane >> 4) << 2;
#pragma unroll
  for (int i = 0; i < 2; ++i) {
#pragma unroll
    for (int jj = 0; jj < 2; ++jj) {
      f32x4 v = (i == 0) ? (jj == 0 ? acc00 : acc01)
                         : (jj == 0 ? acc10 : acc11);
      int row0 = m0 + wm + i * 16 + rbase;
      int col = n0 + wn + jj * 16 + lr;
#pragma unroll
      for (int q = 0; q < 4; ++q)
        Cout[(size_t)(row0 + q) * 256 + col] = v[q];
    }
  }
}

// ------ logits GEMM: 128x128 tile, K=256 in two 64KB LDS stages, NT C ------
__global__ __launch_bounds__(512) void gemm128(const u16* __restrict__ A,
    const u16* __restrict__ Bw, float* __restrict__ Cout, int N) {
  __shared__ u16 s_a[128 * 128];
  __shared__ u16 s_b[128 * 128];
  int tid = threadIdx.x;
  int n0 = blockIdx.x * 128, m0 = blockIdx.y * 128;
  int lane = tid & 63, w = tid >> 6;
  int wm = (w >> 1) * 32;  // 0,32,64,96
  int wn = (w & 1) * 64;   // 0,64
  int lr = lane & 15, lk = (lane >> 4) << 3;
  f32x4 acc[2][4];
#pragma unroll
  for (int i = 0; i < 2; ++i)
#pragma unroll
    for (int t = 0; t < 4; ++t) acc[i][t] = {0.f, 0.f, 0.f, 0.f};
#pragma unroll
  for (int kc = 0; kc < 2; ++kc) {
    if (kc) __syncthreads();
    for (int c = tid; c < 2048; c += 512) {
      int row = c >> 4;
      int ec = (c & 15) << 3;
      short8_t va =
          *(const short8_t*)(A + (size_t)(m0 + row) * 256 + kc * 128 + ec);
      short8_t vb =
          *(const short8_t*)(Bw + (size_t)(n0 + row) * 256 + kc * 128 + ec);
      int sw = ec ^ ((row & 7) << 3);
      *(short8_t*)(&s_a[row * 128 + sw]) = va;
      *(short8_t*)(&s_b[row * 128 + sw]) = vb;
    }
    __syncthreads();
#pragma unroll
    for (int ks = 0; ks < 4; ++ks) {
      int ke = ks * 32 + lk;
      int r0 = wm + lr, r1 = wm + 16 + lr;
      short8_t a0 =
          *(const short8_t*)(&s_a[r0 * 128 + (ke ^ ((r0 & 7) << 3))]);
      short8_t a1 =
          *(const short8_t*)(&s_a[r1 * 128 + (ke ^ ((r1 & 7) << 3))]);
#pragma unroll
      for (int t = 0; t < 4; ++t) {
        int c0 = wn + t * 16 + lr;
        short8_t b0 =
            *(const short8_t*)(&s_b[c0 * 128 + (ke ^ ((c0 & 7) << 3))]);
        acc[0][t] = __builtin_amdgcn_mfma_f32_16x16x32_bf16(a0, b0, acc[0][t], 0, 0, 0);
        acc[1][t] = __builtin_amdgcn_mfma_f32_16x16x32_bf16(a1, b0, acc[1][t], 0, 0, 0);
      }
    }
  }
  int rbase = (lane >> 4) << 2;
#pragma unroll
  for (int i = 0; i < 2; ++i) {
#pragma unroll
    for (int t = 0; t < 4; ++t) {
      int row0 = m0 + wm + i * 16 + rbase;
      int col = n0 + wn + t * 16 + lr;
#pragma unroll
      for (int q = 0; q < 4; ++q)
        __builtin_nontemporal_store(acc[i][t][q],
                                    &Cout[(size_t)(row0 + q) * (size_t)N + col]);
    }
  }
}

// ------- input compression attention: softmax over slots, then mask ---------
__global__ __launch_bounds__(128) void attn_in_k(const float* __restrict__ Qi,
    const float* __restrict__ Ksl, const int* __restrict__ am,
    float* __restrict__ Aout) {
  int bs = blockIdx.x, t = threadIdx.x;
  __shared__ float s_q[DM];
  __shared__ float sred[2];
  s_q[t] = Qi[(size_t)bs * DM + t];
  s_q[t + 128] = Qi[(size_t)bs * DM + t + 128];
  __syncthreads();
  const float* kr = Ksl + (size_t)t * DM;
  float sc = 0.f;
#pragma unroll 8
  for (int d = 0; d < DM; ++d) sc += s_q[d] * kr[d];
  sc *= 0.0625f;
  float mx = sc;
#pragma unroll
  for (int m = 1; m < 64; m <<= 1) mx = fmaxf(mx, __shfl_xor(mx, m));
  if ((t & 63) == 0) sred[t >> 6] = mx;
  __syncthreads();
  mx = fmaxf(sred[0], sred[1]);
  float p = expf(sc - mx);
  float sum = p;
#pragma unroll
  for (int m = 1; m < 64; m <<= 1) sum += __shfl_xor(sum, m);
  __syncthreads();
  if ((t & 63) == 0) sred[t >> 6] = sum;
  __syncthreads();
  sum = sred[0] + sred[1];
  p = (p / sum) * (float)am[bs];
  Aout[(size_t)bs * SL + t] = p;
}

// ---- partial column sums: dpart[sl][b*SL+k] = sum of 32 si; 16 slices ------
__global__ __launch_bounds__(512) void colsum_k(const float* __restrict__ A,
                                                float* __restrict__ dpart) {
  int t = threadIdx.x;
  int b = t >> 7, k = t & (SL - 1);
  int s0 = blockIdx.x * 32;
  const float* ap = A + (size_t)b * SEQ * SL + (size_t)s0 * SL + k;
  float s = 0.f;
#pragma unroll 4
  for (int si = 0; si < 32; ++si) s += ap[(size_t)si * SL];
  dpart[blockIdx.x * 512 + t] = s;
}

// ------ IR[b,k,d] = sum_s A[b,s,k]*Vi[b,s,d] / den;  Hs = H + IR ------------
__global__ __launch_bounds__(256) void irhs_k(const float* __restrict__ A,
    const float* __restrict__ Vi, const float* __restrict__ dpart,
    const float* __restrict__ H, float* __restrict__ Hs) {
  int k = blockIdx.x, b = blockIdx.y, d = threadIdx.x;
  float den = 1e-8f;
#pragma unroll
  for (int i = 0; i < 16; ++i) den += dpart[i * 512 + b * SL + k];
  const float* ap = A + (size_t)b * SEQ * SL + k;
  const float* vp = Vi + (size_t)b * SEQ * DM + d;
  float s = 0.f;
#pragma unroll 4
  for (int si = 0; si < SEQ; ++si)
    s += ap[(size_t)si * SL] * vp[(size_t)si * DM];
  Hs[((size_t)b * SL + k) * DM + d] = H[(size_t)k * DM + d] + s / den;
}

// -------------------- bilinear all-pairs slot mixing ------------------------
// ONE pair (i,j) per wave; block (j, ic) = 4 waves covering i in [4ic,4ic+4).
// W streamed with nontemporal loads (no reuse; keep L2 for small tensors).
// MODE 0: bf16 W. MODE 1: f32 W + NT-write bf16 slabs. MODE 2: f32, no write.
template <int MODE>
__global__ __launch_bounds__(256, 2) void bilinear_k(
    const float* __restrict__ Hs, const void* __restrict__ Wsv,
    const void* __restrict__ Wtv, u16* __restrict__ Wsb,
    u16* __restrict__ Wtb, float* __restrict__ part) {
  constexpr int QN = (MODE == 0) ? 8 : 4;
  int j = blockIdx.x, ic = blockIdx.y, tid = threadIdx.x;
  int wv = tid >> 6, ln = tid & 63;
  __shared__ float s_hs[NB][4][DM];   // 16 KB
  __shared__ float s_int[4][NB][RK];  // 2 KB, per-wave slot
  __shared__ float s_acc[4][NB][DM];  // 16 KB, per-wave slot
  int i0 = ic * 4;
  for (int c = tid; c < (NB * 4 * DM) / 4; c += 256) {
    int fi = c * 4;
    int b = fi >> 10, rest = fi & 1023;
    *(float4*)(&s_hs[0][0][0] + fi) =
        *(const float4*)(Hs + (size_t)b * SL * DM + (size_t)i0 * DM + rest);
  }
  __syncthreads();
  int il = wv;
  int i = i0 + il;
  float iacc[NB][QN];
#pragma unroll
  for (int b = 0; b < NB; ++b)
#pragma unroll
    for (int q = 0; q < QN; ++q) iacc[b][q] = 0.f;
  if (i != j) {
    size_t slab = (size_t)(i * SL + j) * (DM * RK);
    if constexpr (MODE == 0) {
      const u16* wp = (const u16*)Wsv + slab;
      const u16* tp = (const u16*)Wtv + slab;
      short8_t wsr[16], wtr[16];
#pragma unroll
      for (int t = 0; t < 16; ++t)
        wsr[t] = __builtin_nontemporal_load(
            (const short8_t*)(wp + t * 512 + ln * 8));
#pragma unroll
      for (int t = 0; t < 16; ++t)
        wtr[t] = __builtin_nontemporal_load(
            (const short8_t*)(tp + t * 512 + ln * 8));
      float racc[NB][8];
#pragma unroll
      for (int b = 0; b < NB; ++b)
#pragma unroll
        for (int q = 0; q < 8; ++q) racc[b][q] = 0.f;
#pragma unroll
      for (int t = 0; t < 16; ++t) {
        int d = t * 16 + (ln >> 2);
        float h0 = s_hs[0][il][d], h1 = s_hs[1][il][d];
        float h2 = s_hs[2][il][d], h3 = s_hs[3][il][d];
#pragma unroll
        for (int q = 0; q < 8; ++q) {
          float wf = bf2f((u16)wsr[t][q]);
          racc[0][q] += h0 * wf;
          racc[1][q] += h1 * wf;
          racc[2][q] += h2 * wf;
          racc[3][q] += h3 * wf;
        }
      }
#pragma unroll
      for (int m = 4; m <= 32; m <<= 1)
#pragma unroll
        for (int b = 0; b < NB; ++b)
#pragma unroll
          for (int q = 0; q < 8; ++q) racc[b][q] += __shfl_xor(racc[b][q], m);
      if ((ln >> 2) == 0) {
        int r0 = (ln & 3) * 8;
#pragma unroll
        for (int b = 0; b < NB; ++b)
#pragma unroll
          for (int q = 0; q < 8; ++q) s_int[wv][b][r0 + q] = racc[b][q];
      }
      // same-wave LDS write->read: in-order, no barrier needed
#pragma unroll
      for (int t = 0; t < 16; ++t) {
        int r = t * 2 + (ln >> 5);
        float v0 = s_int[wv][0][r], v1 = s_int[wv][1][r];
        float v2 = s_int[wv][2][r], v3 = s_int[wv][3][r];
#pragma unroll
        for (int q = 0; q < 8; ++q) {
          float wf = bf2f((u16)wtr[t][q]);
          iacc[0][q] += v0 * wf;
          iacc[1][q] += v1 * wf;
          iacc[2][q] += v2 * wf;
          iacc[3][q] += v3 * wf;
        }
      }
    } else {
      const float* wp = (const float*)Wsv + slab;
      const float* tp = (const float*)Wtv + slab;
      f32x4 wsr[32];
#pragma unroll
      for (int t = 0; t < 32; ++t)
        wsr[t] =
            __builtin_nontemporal_load((const f32x4*)(wp + t * 256 + ln * 4));
      float racc[NB][4];
#pragma unroll
      for (int b = 0; b < NB; ++b)
#pragma unroll
        for (int q = 0; q < 4; ++q) racc[b][q] = 0.f;
#pragma unroll
      for (int t = 0; t < 32; ++t) {
        f32x4 w4 = wsr[t];
        int d = t * 8 + (ln >> 3);
        float h0 = s_hs[0][il][d], h1 = s_hs[1][il][d];
        float h2 = s_hs[2][il][d], h3 = s_hs[3][il][d];
        racc[0][0] += h0 * w4[0]; racc[0][1] += h0 * w4[1];
        racc[0][2] += h0 * w4[2]; racc[0][3] += h0 * w4[3];
        racc[1][0] += h1 * w4[0]; racc[1][1] += h1 * w4[1];
        racc[1][2] += h1 * w4[2]; racc[1][3] += h1 * w4[3];
        racc[2][0] += h2 * w4[0]; racc[2][1] += h2 * w4[1];
        racc[2][2] += h2 * w4[2]; racc[2][3] += h2 * w4[3];
        racc[3][0] += h3 * w4[0]; racc[3][1] += h3 * w4[1];
        racc[3][2] += h3 * w4[2]; racc[3][3] += h3 * w4[3];
        if constexpr (MODE == 1) {
          u64 pk = (u64)((unsigned)f2bf(w4[0]) | ((unsigned)f2bf(w4[1]) << 16)) |
                   ((u64)((unsigned)f2bf(w4[2]) | ((unsigned)f2bf(w4[3]) << 16))
                    << 32);
          __builtin_nontemporal_store(pk, (u64*)(Wsb + slab + t * 256 + ln * 4));
        }
      }
#pragma unroll
      for (int m = 8; m <= 32; m <<= 1)
#pragma unroll
        for (int b = 0; b < NB; ++b)
#pragma unroll
          for (int q = 0; q < 4; ++q) racc[b][q] += __shfl_xor(racc[b][q], m);
      if ((ln >> 3) == 0) {
        int r0 = (ln & 7) * 4;
#pragma unroll
        for (int b = 0; b < NB; ++b)
#pragma unroll
          for (int q = 0; q < 4; ++q) s_int[wv][b][r0 + q] = racc[b][q];
      }
#pragma unroll
      for (int c8 = 0; c8 < 4; ++c8) {
        f32x4 wtr[8];
#pragma unroll
        for (int t = 0; t < 8; ++t)
          wtr[t] = __builtin_nontemporal_load(
              (const f32x4*)(tp + (c8 * 8 + t) * 256 + ln * 4));
#pragma unroll
        for (int t = 0; t < 8; ++t) {
          int r = c8 * 8 + t;
          f32x4 w4 = wtr[t];
          float v0 = s_int[wv][0][r], v1 = s_int[wv][1][r];
          float v2 = s_int[wv][2][r], v3 = s_int[wv][3][r];
          iacc[0][0] += v0 * w4[0]; iacc[0][1] += v0 * w4[1];
          iacc[0][2] += v0 * w4[2]; iacc[0][3] += v0 * w4[3];
          iacc[1][0] += v1 * w4[0]; iacc[1][1] += v1 * w4[1];
          iacc[1][2] += v1 * w4[2]; iacc[1][3] += v1 * w4[3];
          iacc[2][0] += v2 * w4[0]; iacc[2][1] += v2 * w4[1];
          iacc[2][2] += v2 * w4[2]; iacc[2][3] += v2 * w4[3];
          iacc[3][0] += v3 * w4[0]; iacc[3][1] += v3 * w4[1];
          iacc[3][2] += v3 * w4[2]; iacc[3][3] += v3 * w4[3];
          if constexpr (MODE == 1) {
            u64 pk =
                (u64)((unsigned)f2bf(w4[0]) | ((unsigned)f2bf(w4[1]) << 16)) |
                ((u64)((unsigned)f2bf(w4[2]) | ((unsigned)f2bf(w4[3]) << 16))
                 << 32);
            __builtin_nontemporal_store(pk,
                                        (u64*)(Wtb + slab + r * 256 + ln * 4));
          }
        }
      }
    }
  }
  if constexpr (MODE == 0) {
#pragma unroll
    for (int b = 0; b < NB; ++b)
#pragma unroll
      for (int q = 0; q < 8; ++q) iacc[b][q] += __shfl_xor(iacc[b][q], 32);
    if (ln < 32) {
#pragma unroll
      for (int b = 0; b < NB; ++b)
#pragma unroll
        for (int q = 0; q < 8; ++q) s_acc[wv][b][ln * 8 + q] = iacc[b][q];
    }
  } else {
#pragma unroll
    for (int b = 0; b < NB; ++b)
#pragma unroll
      for (int q = 0; q < 4; ++q) s_acc[wv][b][ln * 4 + q] = iacc[b][q];
  }
  __syncthreads();
  for (int c = tid; c < NB * DM; c += 256) {
    int b = c >> 8, d = c & 255;
    float s = s_acc[0][b][d] + s_acc[1][b][d] + s_acc[2][b][d] + s_acc[3][b][d];
    part[(((size_t)ic * NB + b) * SL + j) * DM + d] = s;
  }
}

// ------- reduce partials + relu + residual + LayerNorm (per (b,j) row) ------
__global__ __launch_bounds__(256) void ln_k(float* __restrict__ Hs,
    const float* __restrict__ part, const float* __restrict__ g,
    const float* __restrict__ be, int last, u16* __restrict__ Hs_bf) {
  int j = blockIdx.x, b = blockIdx.y, d = threadIdx.x;
  size_t base = ((size_t)b * SL + j) * DM + d;
  float inf = 0.f;
#pragma unroll
  for (int icc = 0; icc < NCHUNK; ++icc)
    inf += part[(((size_t)icc * NB + b) * SL + j) * DM + d];
  float h = Hs[base] + fmaxf(inf, 0.f);
  float s1 = h, s2 = h * h;
#pragma unroll
  for (int m = 1; m < 64; m <<= 1) {
    s1 += __shfl_xor(s1, m);
    s2 += __shfl_xor(s2, m);
  }
  __shared__ float r1[4], r2[4];
  int wv = d >> 6;
  if ((d & 63) == 0) { r1[wv] = s1; r2[wv] = s2; }
  __syncthreads();
  s1 = r1[0] + r1[1] + r1[2] + r1[3];
  s2 = r2[0] + r2[1] + r2[2] + r2[3];
  float mu = s1 * (1.f / 256.f);
  float var = s2 * (1.f / 256.f) - mu * mu;
  float o = (h - mu) * rsqrtf(var + 1e-5f) * g[d] + be[d];
  Hs[base] = o;
  if (last) Hs_bf[base] = f2bf(o);
}

// ----------------- output expansion attention + Y (bf16) --------------------
__global__ __launch_bounds__(128) void attn_out_k(const float* __restrict__ Qo,
    const float* __restrict__ Kf, const float* __restrict__ Vf,
    u16* __restrict__ Ybf) {
  int bs = blockIdx.x, t = threadIdx.x;
  int b = bs >> 9;
  __shared__ float s_q[DM];
  __shared__ float s_p[SL];
  __shared__ float sred[2];
  s_q[t] = Qo[(size_t)bs * DM + t];
  s_q[t + 128] = Qo[(size_t)bs * DM + t + 128];
  __syncthreads();
  const float* kr = Kf + ((size_t)b * SL + t) * DM;
  float sc = 0.f;
#pragma unroll 8
  for (int d = 0; d < DM; ++d) sc += s_q[d] * kr[d];
  sc *= 0.0625f;
  float mx = sc;
#pragma unroll
  for (int m = 1; m < 64; m <<= 1) mx = fmaxf(mx, __shfl_xor(mx, m));
  if ((t & 63) == 0) sred[t >> 6] = mx;
  __syncthreads();
  mx = fmaxf(sred[0], sred[1]);
  float p = expf(sc - mx);
  float sum = p;
#pragma unroll
  for (int m = 1; m < 64; m <<= 1) sum += __shfl_xor(sum, m);
  __syncthreads();
  if ((t & 63) == 0) sred[t >> 6] = sum;
  __syncthreads();
  sum = sred[0] + sred[1];
  s_p[t] = p / sum;
  __syncthreads();
  for (int dd = t; dd < DM; dd += 128) {
    float y = 0.f;
    const float* vp = Vf + (size_t)b * SL * DM + dd;
#pragma unroll 8
    for (int k2 = 0; k2 < SL; ++k2) y += s_p[k2] * vp[(size_t)k2 * DM];
    Ybf[(size_t)bs * DM + dd] = f2bf(y);
  }
}

extern "C" void kernel_launch(void* const* d_in, const int* in_sizes, int n_in,
                              void* d_out, int out_size, void* d_ws,
                              size_t ws_size, hipStream_t stream) {
  (void)in_sizes; (void)n_in; (void)out_size;
  const int* ids = (const int*)d_in[0];
  const int* amask = (const int*)d_in[1];
  const float* tok = (const float*)d_in[2];
  const float* pos = (const float*)d_in[3];
  const float* Hsl = (const float*)d_in[4];
  const float* Ws = (const float*)d_in[5];
  const float* Wt = (const float*)d_in[6];
  const float* wq_in = (const float*)d_in[7];
  const float* wk_sl = (const float*)d_in[8];
  const float* wv_in = (const float*)d_in[9];
  const float* wq_out = (const float*)d_in[10];
  const float* wk_fin = (const float*)d_in[11];
  const float* wv_fin = (const float*)d_in[12];
  const float* w_out = (const float*)d_in[13];
  const float* lng = (const float*)d_in[14];
  const float* lnb = (const float*)d_in[15];

  char* base = (char*)d_ws;
  size_t used = 0;
  auto carve = [&](size_t bytes) {
    void* r = base + used;
    used += (bytes + 255) & ~(size_t)255;
    return r;
  };
  u16* x_bf = (u16*)carve((size_t)2048 * 256 * 2);
  float* Qi = (float*)carve((size_t)2048 * 256 * 4);  // Qi,Vi,Qo contiguous
  float* Vi = (float*)carve((size_t)2048 * 256 * 4);
  float* Qo = (float*)carve((size_t)2048 * 256 * 4);
  float* Ksl = (float*)carve((size_t)128 * 256 * 4);
  float* Aat = (float*)carve((size_t)4 * 512 * 128 * 4);
  float* dpart = (float*)carve((size_t)16 * 512 * 4);
  float* Hst = (float*)carve((size_t)4 * 128 * 256 * 4);
  u16* Hs_bf = (u16*)carve((size_t)4 * 128 * 256 * 2);
  float* part = (float*)carve((size_t)NCHUNK * 4 * 128 * 256 * 4);
  float* Kf = (float*)carve((size_t)4 * 128 * 256 * 4);  // Kf,Vf contiguous
  float* Vf = (float*)carve((size_t)4 * 128 * 256 * 4);
  u16* Ybf = (u16*)carve((size_t)2048 * 256 * 2);
  u16* wbase = (u16*)carve((size_t)6 * 65536 * 2);  // 6 square weights
  u16* Hbf = (u16*)carve((size_t)128 * 256 * 2);
  u16* w_out_bf = (u16*)carve((size_t)32000 * 256 * 2);
  const size_t WN = (size_t)128 * 128 * 256 * 32;  // elems of each W tensor
  bool bigws = (used + 2 * WN * 2 + 512) <= ws_size;
  u16* Ws_bf = nullptr;
  u16* Wt_bf = nullptr;
  if (bigws) {
    Ws_bf = (u16*)carve(WN * 2);
    Wt_bf = (u16*)carve(WN * 2);
  }

  // batched conversions: 6 square weights + H in one launch, w_out in another
  CvtJobs cj;
  cj.src[0] = wq_in; cj.src[1] = wk_sl; cj.src[2] = wv_in;
  cj.src[3] = wq_out; cj.src[4] = wk_fin; cj.src[5] = wv_fin;
  cj.src[6] = Hsl;
  cvt_all_k<<<dim3(64, 7), 256, 0, stream>>>(cj, wbase, Hbf);
  cvt_k<<<2048, 256, 0, stream>>>(w_out, w_out_bf, (int)(32000 * 256 / 4));

  embed_k<<<2048, 256, 0, stream>>>(ids, tok, pos, x_bf);
  // Qi (q=0), Vi (q=2), Qo (q=3) in one z-batched launch
  gemm_nt3<<<dim3(32, 4, 3), 256, 0, stream>>>(x_bf, wbase, Qi, 0, 2, 3,
                                               (size_t)2048 * 256);
  gemm_nt<<<dim3(2, 4), 256, 0, stream>>>(Hbf, wbase + (size_t)1 * 65536, Ksl,
                                          256);
  attn_in_k<<<2048, 128, 0, stream>>>(Qi, Ksl, amask, Aat);
  colsum_k<<<16, 512, 0, stream>>>(Aat, dpart);
  irhs_k<<<dim3(128, 4), 256, 0, stream>>>(Aat, Vi, dpart, Hsl, Hst);
  for (int step = 0; step < 6; ++step) {
    if (bigws) {
      if (step == 0)
        bilinear_k<1><<<dim3(SL, 32), 256, 0, stream>>>(Hst, Ws, Wt, Ws_bf,
                                                        Wt_bf, part);
      else
        bilinear_k<0><<<dim3(SL, 32), 256, 0, stream>>>(Hst, Ws_bf, Wt_bf,
                                                        nullptr, nullptr, part);
    } else {
      bilinear_k<2><<<dim3(SL, 32), 256, 0, stream>>>(Hst, Ws, Wt, nullptr,
                                                      nullptr, part);
    }
    ln_k<<<dim3(128, 4), 256, 0, stream>>>(Hst, part, lng + step * DM,
                                           lnb + step * DM, step == 5 ? 1 : 0,
                                           Hs_bf);
  }
  // Kf (q=4), Vf (q=5) in one z-batched launch
  gemm_nt3<<<dim3(8, 4, 2), 256, 0, stream>>>(Hs_bf, wbase, Kf, 4, 5, 5,
                                              (size_t)4 * 128 * 256);
  attn_out_k<<<2048, 128, 0, stream>>>(Qo, Kf, Vf, Ybf);
  gemm128<<<dim3(250, 16), 512, 0, stream>>>(Ybf, w_out_bf, (float*)d_out,
                                             32000);
}